// Round 1
// baseline (278.598 us; speedup 1.0000x reference)
//
#include <hip/hip_runtime.h>
#include <math.h>

typedef unsigned short u16;
typedef short bf16x8 __attribute__((ext_vector_type(8)));
typedef float f32x4 __attribute__((ext_vector_type(4)));

// ---------- helpers ----------
__device__ __forceinline__ u16 f2bf(float f) {
    union { float f; unsigned u; } x; x.f = f;
    unsigned u = x.u;
    unsigned r = (u + 0x7fffu + ((u >> 16) & 1u)) >> 16;   // RNE, no NaN in data
    return (u16)r;
}
__device__ __forceinline__ unsigned pack2(float a, float b) {
    return (unsigned)f2bf(a) | ((unsigned)f2bf(b) << 16);
}
__device__ __forceinline__ f32x4 mfma16(bf16x8 a, bf16x8 b, f32x4 c) {
    return __builtin_amdgcn_mfma_f32_16x16x32_bf16(a, b, c, 0, 0, 0);
}
__device__ __forceinline__ void gload_lds16(const void* g, void* l) {
    __builtin_amdgcn_global_load_lds((const __attribute__((address_space(1))) void*)g,
                                     (__attribute__((address_space(3))) void*)l,
                                     16, 0, 0);
}

// ---------- fp32 -> bf16 cast (vectorized) ----------
__global__ void cvt_bf16(const float* __restrict__ X, u16* __restrict__ Y) {
    int i = (blockIdx.x * 256 + threadIdx.x) * 4;
    float4 v = *(const float4*)(X + i);
    uint2 o;
    o.x = pack2(v.x, v.y);
    o.y = pack2(v.z, v.w);
    *(uint2*)(Y + i) = o;
}

// ---------- W[R][C] fp32 -> Wt[C][R] bf16 (LDS-tiled transpose) ----------
__global__ void transpose_cvt(const float* __restrict__ W, u16* __restrict__ Wt,
                              int R, int C) {
    __shared__ u16 tile[32][33];
    int tx = threadIdx.x & 31, ty = threadIdx.x >> 5;  // 32 x 8
    int bx = blockIdx.x * 32;  // col of W
    int by = blockIdx.y * 32;  // row of W
#pragma unroll
    for (int r = ty; r < 32; r += 8)
        tile[r][tx] = f2bf(W[(size_t)(by + r) * C + bx + tx]);
    __syncthreads();
#pragma unroll
    for (int r = ty; r < 32; r += 8)
        Wt[(size_t)(bx + r) * R + by + tx] = tile[tx][r];
}

// ---------- GEMM: C[M][N] = A[M][K] * Bt[N][K]^T  (bf16 in, fp32 out) ----------
// 128x128 tile, BK=32, 4 waves, 4x4 16x16x32 MFMA frags per wave (m97 structure)
__global__ __launch_bounds__(256) void gemm_bt(const u16* __restrict__ A,
                                               const u16* __restrict__ Bt,
                                               float* __restrict__ C,
                                               int M, int N, int K) {
    __shared__ u16 lA[128 * 32];
    __shared__ u16 lB[128 * 32];
    const int tid = threadIdx.x;
    const int wave = tid >> 6, lane = tid & 63;
    const int l15 = lane & 15, l4 = lane >> 4;
    const int m0 = blockIdx.y * 128, n0 = blockIdx.x * 128;
    const int wm = (wave >> 1) * 64, wn = (wave & 1) * 64;
    f32x4 acc[4][4] = {};
    for (int k0 = 0; k0 < K; k0 += 32) {
#pragma unroll
        for (int it = 0; it < 2; ++it) {
            int c = wave * 128 + it * 64 + lane;
            int r = c >> 2, col = (c & 3) << 3;
            gload_lds16(A + (size_t)(m0 + r) * K + k0 + col,
                        &lA[(size_t)(wave * 128 + it * 64) * 8]);
            gload_lds16(Bt + (size_t)(n0 + r) * K + k0 + col,
                        &lB[(size_t)(wave * 128 + it * 64) * 8]);
        }
        __syncthreads();   // drains vmcnt(0) for global_load_lds, then barrier
        bf16x8 af[4], bf[4];
#pragma unroll
        for (int mi = 0; mi < 4; ++mi)
            af[mi] = *(const bf16x8*)(&lA[(wm + mi * 16 + l15) * 32 + l4 * 8]);
#pragma unroll
        for (int ni = 0; ni < 4; ++ni)
            bf[ni] = *(const bf16x8*)(&lB[(wn + ni * 16 + l15) * 32 + l4 * 8]);
#pragma unroll
        for (int mi = 0; mi < 4; ++mi)
#pragma unroll
            for (int ni = 0; ni < 4; ++ni)
                acc[mi][ni] = mfma16(af[mi], bf[ni], acc[mi][ni]);
        __syncthreads();
    }
#pragma unroll
    for (int mi = 0; mi < 4; ++mi)
#pragma unroll
        for (int ni = 0; ni < 4; ++ni)
#pragma unroll
            for (int i = 0; i < 4; ++i) {
                int r = m0 + wm + mi * 16 + l4 * 4 + i;
                int cc = n0 + wn + ni * 16 + l15;
                C[(size_t)r * N + cc] = acc[mi][ni][i];
            }
}

// ---------- RoPE + pack: C1[4096][3072] fp32 -> qb,kb (B,H,T,Dh) bf16, vt (B,H,Dh,T) bf16 ----------
__global__ void rope_pack(const float* __restrict__ C1, u16* __restrict__ qb,
                          u16* __restrict__ kb, u16* __restrict__ vt) {
    int bh = blockIdx.x >> 5;          // 0..31
    int tt = blockIdx.x & 31;          // 0..31
    int tq = tt * 64 + threadIdx.x;    // t index, 64 threads/block
    int b = bh >> 4, h = bh & 15;
    const float* base = C1 + (size_t)(b * 2048 + tq) * 3072 + h * 64;

    float cs[32], sn[32];
#pragma unroll
    for (int d = 0; d < 32; ++d) {
        float invf = powf(10000.0f, -(float)d / 32.0f);
        float ang = (float)tq * invf;
        sn[d] = sinf(ang);
        cs[d] = cosf(ang);
    }
    float v[64];
    // ---- q ----
#pragma unroll
    for (int j = 0; j < 16; ++j) *(float4*)(&v[j * 4]) = *(const float4*)(base + j * 4);
#pragma unroll
    for (int d = 0; d < 32; ++d) {
        float a = v[d], bb = v[d + 32];
        v[d] = a * cs[d] - bb * sn[d];
        v[d + 32] = bb * cs[d] + a * sn[d];
    }
    {
        u16* dst = qb + ((size_t)bh * 2048 + tq) * 64;
#pragma unroll
        for (int j = 0; j < 8; ++j) {
            uint4 pk;
            pk.x = pack2(v[j * 8 + 0], v[j * 8 + 1]);
            pk.y = pack2(v[j * 8 + 2], v[j * 8 + 3]);
            pk.z = pack2(v[j * 8 + 4], v[j * 8 + 5]);
            pk.w = pack2(v[j * 8 + 6], v[j * 8 + 7]);
            *(uint4*)(dst + j * 8) = pk;
        }
    }
    // ---- k ----
#pragma unroll
    for (int j = 0; j < 16; ++j) *(float4*)(&v[j * 4]) = *(const float4*)(base + 1024 + j * 4);
#pragma unroll
    for (int d = 0; d < 32; ++d) {
        float a = v[d], bb = v[d + 32];
        v[d] = a * cs[d] - bb * sn[d];
        v[d + 32] = bb * cs[d] + a * sn[d];
    }
    {
        u16* dst = kb + ((size_t)bh * 2048 + tq) * 64;
#pragma unroll
        for (int j = 0; j < 8; ++j) {
            uint4 pk;
            pk.x = pack2(v[j * 8 + 0], v[j * 8 + 1]);
            pk.y = pack2(v[j * 8 + 2], v[j * 8 + 3]);
            pk.z = pack2(v[j * 8 + 4], v[j * 8 + 5]);
            pk.w = pack2(v[j * 8 + 6], v[j * 8 + 7]);
            *(uint4*)(dst + j * 8) = pk;
        }
    }
    // ---- v (transposed store: vt[bh][dh][t]) ----
#pragma unroll
    for (int j = 0; j < 16; ++j) *(float4*)(&v[j * 4]) = *(const float4*)(base + 2048 + j * 4);
#pragma unroll
    for (int d = 0; d < 64; ++d)
        vt[((size_t)bh * 64 + d) * 2048 + tq] = f2bf(v[d]);
}

// ---------- causal flash attention ----------
// grid (32 qtiles, 32 bh), 256 threads = 4 waves x 16 q-rows; kv-blocks of 64
__global__ __launch_bounds__(256) void flash(const u16* __restrict__ qb,
                                             const u16* __restrict__ kb,
                                             const u16* __restrict__ vt,
                                             u16* __restrict__ ao) {
    __shared__ u16 lK[64 * 72];      // [kv][dh], stride 72
    __shared__ u16 lV[64 * 72];      // [dh][kv], stride 72
    __shared__ u16 lP[4][16 * 72];   // per-wave P tile [q][kv]
    const int bh = blockIdx.y;
    const int b = bh >> 4, h = bh & 15;
    const int q0 = blockIdx.x * 64;
    const int tid = threadIdx.x;
    const int wave = tid >> 6, lane = tid & 63;
    const int l15 = lane & 15, l4 = lane >> 4;
    const u16* qptr = qb + (size_t)bh * 2048 * 64;
    const u16* kptr = kb + (size_t)bh * 2048 * 64;
    const u16* vptr = vt + (size_t)bh * 64 * 2048;

    const int qrow = q0 + wave * 16 + l15;
    bf16x8 qf0 = *(const bf16x8*)(qptr + (size_t)qrow * 64 + l4 * 8);
    bf16x8 qf1 = *(const bf16x8*)(qptr + (size_t)qrow * 64 + 32 + l4 * 8);

    f32x4 O[4] = {};
    float mrun[4], lrun[4];
#pragma unroll
    for (int i = 0; i < 4; ++i) { mrun[i] = -INFINITY; lrun[i] = 0.f; }

    const int nkv = blockIdx.x + 1;
    const int sr = tid >> 2;          // staging row 0..63
    const int sc = (tid & 3) * 16;    // staging col (16 elems)

    for (int kvb = 0; kvb < nkv; ++kvb) {
        const int kv0 = kvb * 64;
        __syncthreads();
        *(uint4*)(&lK[sr * 72 + sc])     = *(const uint4*)(kptr + (size_t)(kv0 + sr) * 64 + sc);
        *(uint4*)(&lK[sr * 72 + sc + 8]) = *(const uint4*)(kptr + (size_t)(kv0 + sr) * 64 + sc + 8);
        *(uint4*)(&lV[sr * 72 + sc])     = *(const uint4*)(vptr + (size_t)sr * 2048 + kv0 + sc);
        *(uint4*)(&lV[sr * 72 + sc + 8]) = *(const uint4*)(vptr + (size_t)sr * 2048 + kv0 + sc + 8);
        __syncthreads();

        // S = Q K^T for 64 kv cols
        f32x4 S[4] = {};
#pragma unroll
        for (int c = 0; c < 4; ++c) {
            bf16x8 kf0 = *(const bf16x8*)(&lK[(c * 16 + l15) * 72 + l4 * 8]);
            bf16x8 kf1 = *(const bf16x8*)(&lK[(c * 16 + l15) * 72 + 32 + l4 * 8]);
            S[c] = mfma16(qf0, kf0, S[c]);
            S[c] = mfma16(qf1, kf1, S[c]);
        }
        // scale + causal mask (only diagonal block needs it)
        float p[4][4];
        const bool diag = (kvb == nkv - 1);
#pragma unroll
        for (int c = 0; c < 4; ++c)
#pragma unroll
            for (int i = 0; i < 4; ++i) {
                float s = S[c][i] * 0.125f;
                if (diag) {
                    int kvi = kv0 + c * 16 + l15;
                    int qi = q0 + wave * 16 + l4 * 4 + i;
                    if (kvi > qi) s = -INFINITY;
                }
                p[c][i] = s;
            }
        // online softmax (rows = l4*4+i, reduce over 16 lanes of lane&15)
#pragma unroll
        for (int i = 0; i < 4; ++i) {
            float m = fmaxf(fmaxf(p[0][i], p[1][i]), fmaxf(p[2][i], p[3][i]));
            m = fmaxf(m, __shfl_xor(m, 1));
            m = fmaxf(m, __shfl_xor(m, 2));
            m = fmaxf(m, __shfl_xor(m, 4));
            m = fmaxf(m, __shfl_xor(m, 8));
            float mnew = fmaxf(mrun[i], m);
            float corr = __expf(mrun[i] - mnew);
            float rs = 0.f;
#pragma unroll
            for (int c = 0; c < 4; ++c) {
                float e = __expf(p[c][i] - mnew);
                p[c][i] = e;
                rs += e;
            }
            rs += __shfl_xor(rs, 1);
            rs += __shfl_xor(rs, 2);
            rs += __shfl_xor(rs, 4);
            rs += __shfl_xor(rs, 8);
            lrun[i] = lrun[i] * corr + rs;
            mrun[i] = mnew;
#pragma unroll
            for (int c2 = 0; c2 < 4; ++c2) O[c2][i] *= corr;
        }
        // P -> per-wave LDS (transpose to A-frag layout), then PV
#pragma unroll
        for (int c = 0; c < 4; ++c)
#pragma unroll
            for (int i = 0; i < 4; ++i)
                lP[wave][(l4 * 4 + i) * 72 + c * 16 + l15] = f2bf(p[c][i]);
        asm volatile("s_waitcnt lgkmcnt(0)" ::: "memory");
        __builtin_amdgcn_sched_barrier(0);
#pragma unroll
        for (int ks = 0; ks < 2; ++ks) {
            bf16x8 pf = *(const bf16x8*)(&lP[wave][l15 * 72 + ks * 32 + l4 * 8]);
#pragma unroll
            for (int c2 = 0; c2 < 4; ++c2) {
                bf16x8 vf = *(const bf16x8*)(&lV[(c2 * 16 + l15) * 72 + ks * 32 + l4 * 8]);
                O[c2] = mfma16(pf, vf, O[c2]);
            }
        }
    }
    // epilogue: normalize and store to ao[(b*2048+t)][h*64+dh] as bf16
#pragma unroll
    for (int c2 = 0; c2 < 4; ++c2)
#pragma unroll
        for (int i = 0; i < 4; ++i) {
            int tq = q0 + wave * 16 + l4 * 4 + i;
            float outv = O[c2][i] / lrun[i];
            ao[(size_t)(b * 2048 + tq) * 1024 + h * 64 + c2 * 16 + l15] = f2bf(outv);
        }
}

// ---------- launch ----------
extern "C" void kernel_launch(void* const* d_in, const int* in_sizes, int n_in,
                              void* d_out, int out_size, void* d_ws, size_t ws_size,
                              hipStream_t stream) {
    const float* x    = (const float*)d_in[0];   // (2,2048,1024)
    const float* Wqkv = (const float*)d_in[1];   // (1024,3072)
    const float* Wout = (const float*)d_in[2];   // (1024,1024)
    float* out = (float*)d_out;                  // (2,2048,1024)
    char* ws = (char*)d_ws;

    u16*   xb  = (u16*)(ws + 0);            // 8 MB  (4096x1024 bf16)
    u16*   Wtq = (u16*)(ws + 8388608);      // 6 MB  (3072x1024 bf16)
    u16*   Wto = (u16*)(ws + 14680064);     // 2 MB  (1024x1024 bf16)
    float* C1  = (float*)(ws + 16777216);   // 48 MB (4096x3072 fp32)
    u16*   qb  = (u16*)(ws + 67108864);     // 8 MB  (B,H,T,Dh bf16)
    u16*   kb  = (u16*)(ws + 75497472);     // 8 MB
    u16*   vt  = (u16*)(ws + 83886080);     // 8 MB  (B,H,Dh,T bf16)
    u16*   ao  = (u16*)(ws + 0);            // reuse xb region (GEMM1 done by then)

    hipLaunchKernelGGL(cvt_bf16, dim3(4096), dim3(256), 0, stream, x, xb);
    hipLaunchKernelGGL(transpose_cvt, dim3(96, 32), dim3(256), 0, stream, Wqkv, Wtq, 1024, 3072);
    hipLaunchKernelGGL(transpose_cvt, dim3(32, 32), dim3(256), 0, stream, Wout, Wto, 1024, 1024);
    hipLaunchKernelGGL(gemm_bt, dim3(24, 32), dim3(256), 0, stream, xb, Wtq, C1, 4096, 3072, 1024);
    hipLaunchKernelGGL(rope_pack, dim3(1024), dim3(64), 0, stream, C1, qb, kb, vt);
    hipLaunchKernelGGL(flash, dim3(32, 32), dim3(256), 0, stream, qb, kb, vt, ao);
    hipLaunchKernelGGL(gemm_bt, dim3(8, 32), dim3(256), 0, stream, ao, Wto, out, 4096, 1024, 1024);
}

// Round 2
// 192.096 us; speedup vs baseline: 1.4503x; 1.4503x over previous
//
#include <hip/hip_runtime.h>
#include <math.h>

typedef unsigned short u16;
typedef short bf16x8 __attribute__((ext_vector_type(8)));
typedef float f32x4 __attribute__((ext_vector_type(4)));

// ---------- helpers ----------
__device__ __forceinline__ u16 f2bf(float f) {
    union { float f; unsigned u; } x; x.f = f;
    unsigned u = x.u;
    unsigned r = (u + 0x7fffu + ((u >> 16) & 1u)) >> 16;   // RNE, no NaN in data
    return (u16)r;
}
__device__ __forceinline__ unsigned pack2(float a, float b) {
    return (unsigned)f2bf(a) | ((unsigned)f2bf(b) << 16);
}
__device__ __forceinline__ f32x4 mfma16(bf16x8 a, bf16x8 b, f32x4 c) {
    return __builtin_amdgcn_mfma_f32_16x16x32_bf16(a, b, c, 0, 0, 0);
}
__device__ __forceinline__ void gload_lds16(const void* g, void* l) {
    __builtin_amdgcn_global_load_lds((const __attribute__((address_space(1))) void*)g,
                                     (__attribute__((address_space(3))) void*)l,
                                     16, 0, 0);
}

// ---------- fp32 -> bf16 cast (vectorized) ----------
__global__ void cvt_bf16(const float* __restrict__ X, u16* __restrict__ Y) {
    int i = (blockIdx.x * 256 + threadIdx.x) * 4;
    float4 v = *(const float4*)(X + i);
    uint2 o;
    o.x = pack2(v.x, v.y);
    o.y = pack2(v.z, v.w);
    *(uint2*)(Y + i) = o;
}

// ---------- W[R][C] fp32 -> Wt[C][R] bf16 (LDS-tiled transpose) ----------
__global__ void transpose_cvt(const float* __restrict__ W, u16* __restrict__ Wt,
                              int R, int C) {
    __shared__ u16 tile[32][33];
    int tx = threadIdx.x & 31, ty = threadIdx.x >> 5;  // 32 x 8
    int bx = blockIdx.x * 32;
    int by = blockIdx.y * 32;
#pragma unroll
    for (int r = ty; r < 32; r += 8)
        tile[r][tx] = f2bf(W[(size_t)(by + r) * C + bx + tx]);
    __syncthreads();
#pragma unroll
    for (int r = ty; r < 32; r += 8)
        Wt[(size_t)(bx + r) * R + by + tx] = tile[tx][r];
}

// ---------- GEMM: C[M][N] = A[M][K] * Bt[N][K]^T  (bf16 in, fp32 out) ----------
__global__ __launch_bounds__(256) void gemm_bt(const u16* __restrict__ A,
                                               const u16* __restrict__ Bt,
                                               float* __restrict__ C,
                                               int M, int N, int K) {
    __shared__ u16 lA[128 * 32];
    __shared__ u16 lB[128 * 32];
    const int tid = threadIdx.x;
    const int wave = tid >> 6, lane = tid & 63;
    const int l15 = lane & 15, l4 = lane >> 4;
    const int m0 = blockIdx.y * 128, n0 = blockIdx.x * 128;
    const int wm = (wave >> 1) * 64, wn = (wave & 1) * 64;
    f32x4 acc[4][4] = {};
    for (int k0 = 0; k0 < K; k0 += 32) {
#pragma unroll
        for (int it = 0; it < 2; ++it) {
            int c = wave * 128 + it * 64 + lane;
            int r = c >> 2, col = (c & 3) << 3;
            gload_lds16(A + (size_t)(m0 + r) * K + k0 + col,
                        &lA[(size_t)(wave * 128 + it * 64) * 8]);
            gload_lds16(Bt + (size_t)(n0 + r) * K + k0 + col,
                        &lB[(size_t)(wave * 128 + it * 64) * 8]);
        }
        __syncthreads();
        bf16x8 af[4], bf[4];
#pragma unroll
        for (int mi = 0; mi < 4; ++mi)
            af[mi] = *(const bf16x8*)(&lA[(wm + mi * 16 + l15) * 32 + l4 * 8]);
#pragma unroll
        for (int ni = 0; ni < 4; ++ni)
            bf[ni] = *(const bf16x8*)(&lB[(wn + ni * 16 + l15) * 32 + l4 * 8]);
#pragma unroll
        for (int mi = 0; mi < 4; ++mi)
#pragma unroll
            for (int ni = 0; ni < 4; ++ni)
                acc[mi][ni] = mfma16(af[mi], bf[ni], acc[mi][ni]);
        __syncthreads();
    }
#pragma unroll
    for (int mi = 0; mi < 4; ++mi)
#pragma unroll
        for (int ni = 0; ni < 4; ++ni)
#pragma unroll
            for (int i = 0; i < 4; ++i) {
                int r = m0 + wm + mi * 16 + l4 * 4 + i;
                int cc = n0 + wn + ni * 16 + l15;
                C[(size_t)r * N + cc] = acc[mi][ni][i];
            }
}

// ---------- sin/cos table: tab[0..65535]=cos(t,d), tab[65536..]=sin ----------
__global__ void rope_tab(float* __restrict__ tab) {
    int i = blockIdx.x * 256 + threadIdx.x;   // 65536 = 2048 t x 32 d
    int t = i >> 5, d = i & 31;
    float invf = powf(10000.0f, -(float)d / 32.0f);
    float ang = (float)t * invf;
    tab[i] = cosf(ang);
    tab[i + 65536] = sinf(ang);
}

// ---------- RoPE + pack: C1[4096][3072] fp32 -> qb,kb (B,H,T,Dh) bf16, vt (B,H,Dh,T) bf16 ----------
__global__ void rope_pack(const float* __restrict__ C1, const float* __restrict__ tab,
                          u16* __restrict__ qb, u16* __restrict__ kb, u16* __restrict__ vt) {
    int g = blockIdx.x * 256 + threadIdx.x;   // 65536
    int bh = g >> 11;                          // 0..31
    int tq = g & 2047;
    int b = bh >> 4, h = bh & 15;
    const float* base = C1 + (size_t)(b * 2048 + tq) * 3072 + h * 64;

    float cs[32], sn[32];
    const float* tc = tab + tq * 32;
    const float* ts = tab + 65536 + tq * 32;
#pragma unroll
    for (int j = 0; j < 8; ++j) {
        *(float4*)(&cs[j * 4]) = *(const float4*)(tc + j * 4);
        *(float4*)(&sn[j * 4]) = *(const float4*)(ts + j * 4);
    }
    float v[64];
    // ---- q ----
#pragma unroll
    for (int j = 0; j < 16; ++j) *(float4*)(&v[j * 4]) = *(const float4*)(base + j * 4);
#pragma unroll
    for (int d = 0; d < 32; ++d) {
        float a = v[d], bb = v[d + 32];
        v[d] = a * cs[d] - bb * sn[d];
        v[d + 32] = bb * cs[d] + a * sn[d];
    }
    {
        u16* dst = qb + ((size_t)bh * 2048 + tq) * 64;
#pragma unroll
        for (int j = 0; j < 8; ++j) {
            uint4 pk;
            pk.x = pack2(v[j * 8 + 0], v[j * 8 + 1]);
            pk.y = pack2(v[j * 8 + 2], v[j * 8 + 3]);
            pk.z = pack2(v[j * 8 + 4], v[j * 8 + 5]);
            pk.w = pack2(v[j * 8 + 6], v[j * 8 + 7]);
            *(uint4*)(dst + j * 8) = pk;
        }
    }
    // ---- k ----
#pragma unroll
    for (int j = 0; j < 16; ++j) *(float4*)(&v[j * 4]) = *(const float4*)(base + 1024 + j * 4);
#pragma unroll
    for (int d = 0; d < 32; ++d) {
        float a = v[d], bb = v[d + 32];
        v[d] = a * cs[d] - bb * sn[d];
        v[d + 32] = bb * cs[d] + a * sn[d];
    }
    {
        u16* dst = kb + ((size_t)bh * 2048 + tq) * 64;
#pragma unroll
        for (int j = 0; j < 8; ++j) {
            uint4 pk;
            pk.x = pack2(v[j * 8 + 0], v[j * 8 + 1]);
            pk.y = pack2(v[j * 8 + 2], v[j * 8 + 3]);
            pk.z = pack2(v[j * 8 + 4], v[j * 8 + 5]);
            pk.w = pack2(v[j * 8 + 6], v[j * 8 + 7]);
            *(uint4*)(dst + j * 8) = pk;
        }
    }
    // ---- v (transposed store: vt[bh][dh][t]) ----
#pragma unroll
    for (int j = 0; j < 16; ++j) *(float4*)(&v[j * 4]) = *(const float4*)(base + 2048 + j * 4);
#pragma unroll
    for (int d = 0; d < 64; ++d)
        vt[((size_t)bh * 64 + d) * 2048 + tq] = f2bf(v[d]);
}

// ---------- causal flash attention, paired q-tiles, swapped-QK, P-in-register ----------
// grid (16, 32): block does q-tiles a=blockIdx.x and 31-a  => 33 kv-iters each
__global__ __launch_bounds__(256) void flash2(const u16* __restrict__ qb,
                                              const u16* __restrict__ kb,
                                              const u16* __restrict__ vt,
                                              u16* __restrict__ ao) {
    __shared__ u16 lK[2][64 * 64];   // [kv][d], XOR-swizzled 16B slots
    __shared__ u16 lV[2][64 * 64];   // [d][kv], XOR-swizzled 16B slots
    const int bh = blockIdx.y;
    const int b = bh >> 4, h = bh & 15;
    const int qtA = blockIdx.x;        // 0..15
    const int qtB = 31 - blockIdx.x;   // 16..31
    const int tid = threadIdx.x;
    const int wave = tid >> 6, lane = tid & 63;
    const int l15 = lane & 15, l4 = lane >> 4;
    const u16* qptr = qb + (size_t)bh * 2048 * 64;
    const u16* kptr = kb + (size_t)bh * 2048 * 64;
    const u16* vptr = vt + (size_t)bh * 64 * 2048;

    // Q fragments (B-operand: col=l15=q, k=l4*8+j=d)
    const int qrA = qtA * 64 + wave * 16 + l15;
    const int qrB = qtB * 64 + wave * 16 + l15;
    bf16x8 qA0 = *(const bf16x8*)(qptr + (size_t)qrA * 64 + l4 * 8);
    bf16x8 qA1 = *(const bf16x8*)(qptr + (size_t)qrA * 64 + 32 + l4 * 8);
    bf16x8 qB0 = *(const bf16x8*)(qptr + (size_t)qrB * 64 + l4 * 8);
    bf16x8 qB1 = *(const bf16x8*)(qptr + (size_t)qrB * 64 + 32 + l4 * 8);

    f32x4 OA[4] = {}, OB[4] = {};
    float mA = -INFINITY, lA = 0.f, mB = -INFINITY, lB = 0.f;

    int idxO[4], idxEx[4];
#pragma unroll
    for (int i = 0; i < 4; ++i) idxO[i] = (lane & 48) | (l4 * 4 + i);
#pragma unroll
    for (int r = 0; r < 4; ++r) idxEx[r] = (((2 * l4 + (r >> 1)) & 3) << 4) | l15;

    auto stage = [&](int buf, int kv0) {
#pragma unroll
        for (int it = 0; it < 2; ++it) {
            int cb = wave * 64 + it * 256;       // wave-uniform chunk base
            int c = cb + lane;                   // chunk 0..511
            int r = c >> 3, s = c & 7;
            int sd = (s ^ (r & 7)) * 8;          // inverse-swizzled source slot
            gload_lds16(kptr + (size_t)(kv0 + r) * 64 + sd, &lK[buf][cb * 8]);
            gload_lds16(vptr + (size_t)r * 2048 + kv0 + sd, &lV[buf][cb * 8]);
        }
    };
    auto ldK = [&](int buf, int row, int slot) -> bf16x8 {
        return *(const bf16x8*)(&lK[buf][row * 64 + ((slot ^ (row & 7)) << 3)]);
    };
    auto ldV = [&](int buf, int row, int slot) -> bf16x8 {
        return *(const bf16x8*)(&lV[buf][row * 64 + ((slot ^ (row & 7)) << 3)]);
    };

    // softmax + pack-to-A-frag for one tile (P^T in regs: q=l15, kv=c*16+l4*4+i)
    auto smpack = [&](f32x4 S[4], float& mrun, float& lrun, f32x4 O[4],
                      bf16x8 af[2], bool diag, int kv0, int qrow) {
        float p[4][4];
#pragma unroll
        for (int c = 0; c < 4; ++c)
#pragma unroll
            for (int i = 0; i < 4; ++i) {
                float s = S[c][i] * 0.125f;
                if (diag && (kv0 + c * 16 + l4 * 4 + i > qrow)) s = -INFINITY;
                p[c][i] = s;
            }
        float m = p[0][0];
#pragma unroll
        for (int c = 0; c < 4; ++c)
#pragma unroll
            for (int i = 0; i < 4; ++i) m = fmaxf(m, p[c][i]);
        m = fmaxf(m, __shfl_xor(m, 16));
        m = fmaxf(m, __shfl_xor(m, 32));
        float mnew = fmaxf(mrun, m);
        float corr = __expf(mrun - mnew);
        float rs = 0.f;
#pragma unroll
        for (int c = 0; c < 4; ++c)
#pragma unroll
            for (int i = 0; i < 4; ++i) { p[c][i] = __expf(p[c][i] - mnew); rs += p[c][i]; }
        rs += __shfl_xor(rs, 16);
        rs += __shfl_xor(rs, 32);
        lrun = lrun * corr + rs;
        mrun = mnew;
#pragma unroll
        for (int i = 0; i < 4; ++i) {
            float cf = __shfl(corr, idxO[i]);
#pragma unroll
            for (int c2 = 0; c2 < 4; ++c2) O[c2][i] *= cf;
        }
        unsigned w[4][2];
#pragma unroll
        for (int c = 0; c < 4; ++c) {
            asm("v_cvt_pk_bf16_f32 %0, %1, %2" : "=v"(w[c][0]) : "v"(p[c][0]), "v"(p[c][1]));
            asm("v_cvt_pk_bf16_f32 %0, %1, %2" : "=v"(w[c][1]) : "v"(p[c][2]), "v"(p[c][3]));
        }
#pragma unroll
        for (int ks = 0; ks < 2; ++ks) {
            unsigned a0, a1, a2, a3;
            {
                unsigned lo = __shfl((int)w[2 * ks][0], idxEx[0]);
                unsigned hi = __shfl((int)w[2 * ks + 1][0], idxEx[0]);
                a0 = (l4 < 2) ? lo : hi;
            }
            {
                unsigned lo = __shfl((int)w[2 * ks][1], idxEx[1]);
                unsigned hi = __shfl((int)w[2 * ks + 1][1], idxEx[1]);
                a1 = (l4 < 2) ? lo : hi;
            }
            {
                unsigned lo = __shfl((int)w[2 * ks][0], idxEx[2]);
                unsigned hi = __shfl((int)w[2 * ks + 1][0], idxEx[2]);
                a2 = (l4 < 2) ? lo : hi;
            }
            {
                unsigned lo = __shfl((int)w[2 * ks][1], idxEx[3]);
                unsigned hi = __shfl((int)w[2 * ks + 1][1], idxEx[3]);
                a3 = (l4 < 2) ? lo : hi;
            }
            union { unsigned u[4]; bf16x8 v; } cvt;
            cvt.u[0] = a0; cvt.u[1] = a1; cvt.u[2] = a2; cvt.u[3] = a3;
            af[ks] = cvt.v;
        }
    };

    stage(0, 0);
    for (int kvb = 0; kvb <= qtB; ++kvb) {
        const int cur = kvb & 1;
        const int kv0 = kvb * 64;
        const bool doA = (kvb <= qtA);
        if (kvb < qtB) {
            stage(cur ^ 1, kv0 + 64);
            asm volatile("s_waitcnt vmcnt(4)" ::: "memory");
        } else {
            asm volatile("s_waitcnt vmcnt(0)" ::: "memory");
        }
        __builtin_amdgcn_s_barrier();
        __builtin_amdgcn_sched_barrier(0);

        // QK^T swapped: S'[kv][q] — K/V fragment reads shared by both tiles
        f32x4 SA[4] = {}, SB[4] = {};
#pragma unroll
        for (int c = 0; c < 4; ++c) {
            bf16x8 kf0 = ldK(cur, c * 16 + l15, l4);
            bf16x8 kf1 = ldK(cur, c * 16 + l15, 4 + l4);
            SB[c] = mfma16(kf0, qB0, SB[c]);
            SB[c] = mfma16(kf1, qB1, SB[c]);
            if (doA) {
                SA[c] = mfma16(kf0, qA0, SA[c]);
                SA[c] = mfma16(kf1, qA1, SA[c]);
            }
        }
        bf16x8 aB[2], aA[2];
        smpack(SB, mB, lB, OB, aB, kvb == qtB, kv0, qrB);
        if (doA) smpack(SA, mA, lA, OA, aA, kvb == qtA, kv0, qrA);
#pragma unroll
        for (int ks = 0; ks < 2; ++ks)
#pragma unroll
            for (int c2 = 0; c2 < 4; ++c2) {
                bf16x8 vf = ldV(cur, c2 * 16 + l15, ks * 4 + l4);
                OB[c2] = mfma16(aB[ks], vf, OB[c2]);
                if (doA) OA[c2] = mfma16(aA[ks], vf, OA[c2]);
            }
        __builtin_amdgcn_s_barrier();   // protect buffer overwrite by next stage
    }

    // epilogue: O rows are q'=l4*4+i, cols d=c2*16+l15
#pragma unroll
    for (int i = 0; i < 4; ++i) {
        float lbv = __shfl(lB, idxO[i]);
        float lav = __shfl(lA, idxO[i]);
        float rb = 1.f / lbv, ra = 1.f / lav;
        int qgB = qtB * 64 + wave * 16 + l4 * 4 + i;
        int qgA = qtA * 64 + wave * 16 + l4 * 4 + i;
#pragma unroll
        for (int c2 = 0; c2 < 4; ++c2) {
            ao[(size_t)(b * 2048 + qgB) * 1024 + h * 64 + c2 * 16 + l15] = f2bf(OB[c2][i] * rb);
            ao[(size_t)(b * 2048 + qgA) * 1024 + h * 64 + c2 * 16 + l15] = f2bf(OA[c2][i] * ra);
        }
    }
}

// ---------- launch ----------
extern "C" void kernel_launch(void* const* d_in, const int* in_sizes, int n_in,
                              void* d_out, int out_size, void* d_ws, size_t ws_size,
                              hipStream_t stream) {
    const float* x    = (const float*)d_in[0];   // (2,2048,1024)
    const float* Wqkv = (const float*)d_in[1];   // (1024,3072)
    const float* Wout = (const float*)d_in[2];   // (1024,1024)
    float* out = (float*)d_out;                  // (2,2048,1024)
    char* ws = (char*)d_ws;

    u16*   xb  = (u16*)(ws + 0);            // 8 MB  (4096x1024 bf16)
    u16*   Wtq = (u16*)(ws + 8388608);      // 6 MB  (3072x1024 bf16)
    u16*   Wto = (u16*)(ws + 14680064);     // 2 MB  (1024x1024 bf16)
    float* C1  = (float*)(ws + 16777216);   // 48 MB (4096x3072 fp32)
    u16*   qb  = (u16*)(ws + 67108864);     // 8 MB  (B,H,T,Dh bf16)
    u16*   kb  = (u16*)(ws + 75497472);     // 8 MB
    u16*   vt  = (u16*)(ws + 83886080);     // 8 MB  (B,H,Dh,T bf16)
    float* tab = (float*)(ws + 92274688);   // 512 KB sin/cos table
    u16*   ao  = (u16*)(ws + 0);            // reuse xb region (GEMM1 done by then)

    hipLaunchKernelGGL(cvt_bf16, dim3(4096), dim3(256), 0, stream, x, xb);
    hipLaunchKernelGGL(transpose_cvt, dim3(96, 32), dim3(256), 0, stream, Wqkv, Wtq, 1024, 3072);
    hipLaunchKernelGGL(transpose_cvt, dim3(32, 32), dim3(256), 0, stream, Wout, Wto, 1024, 1024);
    hipLaunchKernelGGL(rope_tab, dim3(256), dim3(256), 0, stream, tab);
    hipLaunchKernelGGL(gemm_bt, dim3(24, 32), dim3(256), 0, stream, xb, Wtq, C1, 4096, 3072, 1024);
    hipLaunchKernelGGL(rope_pack, dim3(256), dim3(256), 0, stream, C1, tab, qb, kb, vt);
    hipLaunchKernelGGL(flash2, dim3(16, 32), dim3(256), 0, stream, qb, kb, vt, ao);
    hipLaunchKernelGGL(gemm_bt, dim3(8, 32), dim3(256), 0, stream, ao, Wto, out, 4096, 1024, 1024);
}

// Round 4
// 170.204 us; speedup vs baseline: 1.6369x; 1.1286x over previous
//
#include <hip/hip_runtime.h>
#include <math.h>

typedef unsigned short u16;
typedef short bf16x8 __attribute__((ext_vector_type(8)));
typedef float f32x4 __attribute__((ext_vector_type(4)));

// ---------- helpers ----------
__device__ __forceinline__ u16 f2bf(float f) {
    union { float f; unsigned u; } x; x.f = f;
    unsigned u = x.u;
    unsigned r = (u + 0x7fffu + ((u >> 16) & 1u)) >> 16;   // RNE, no NaN in data
    return (u16)r;
}
__device__ __forceinline__ unsigned pack2(float a, float b) {
    return (unsigned)f2bf(a) | ((unsigned)f2bf(b) << 16);
}
__device__ __forceinline__ f32x4 mfma16(bf16x8 a, bf16x8 b, f32x4 c) {
    return __builtin_amdgcn_mfma_f32_16x16x32_bf16(a, b, c, 0, 0, 0);
}
__device__ __forceinline__ void gload_lds16(const void* g, void* l) {
    __builtin_amdgcn_global_load_lds((const __attribute__((address_space(1))) void*)g,
                                     (__attribute__((address_space(3))) void*)l,
                                     16, 0, 0);
}

// ---------- fp32 -> bf16 cast (vectorized) ----------
__global__ void cvt_bf16(const float* __restrict__ X, u16* __restrict__ Y) {
    int i = (blockIdx.x * 256 + threadIdx.x) * 4;
    float4 v = *(const float4*)(X + i);
    uint2 o;
    o.x = pack2(v.x, v.y);
    o.y = pack2(v.z, v.w);
    *(uint2*)(Y + i) = o;
}

// ---------- W[R][C] fp32 -> Wt[C][R] bf16 (LDS-tiled transpose) ----------
__global__ void transpose_cvt(const float* __restrict__ W, u16* __restrict__ Wt,
                              int R, int C) {
    __shared__ u16 tile[32][33];
    int tx = threadIdx.x & 31, ty = threadIdx.x >> 5;  // 32 x 8
    int bx = blockIdx.x * 32;
    int by = blockIdx.y * 32;
#pragma unroll
    for (int r = ty; r < 32; r += 8)
        tile[r][tx] = f2bf(W[(size_t)(by + r) * C + bx + tx]);
    __syncthreads();
#pragma unroll
    for (int r = ty; r < 32; r += 8)
        Wt[(size_t)(bx + r) * R + by + tx] = tile[tx][r];
}

// ---------- GEMM: C[M][N] = A[M][K] * Bt[N][K]^T, BK=64, XOR-swizzled LDS ----------
template <bool BF16OUT>
__global__ __launch_bounds__(256) void gemm_bt(const u16* __restrict__ A,
                                               const u16* __restrict__ Bt,
                                               void* __restrict__ Cv,
                                               int M, int N, int K) {
    __shared__ u16 lA[128 * 64];
    __shared__ u16 lB[128 * 64];
    const int tid = threadIdx.x;
    const int wave = tid >> 6, lane = tid & 63;
    const int l15 = lane & 15, l4 = lane >> 4;
    const int m0 = blockIdx.y * 128, n0 = blockIdx.x * 128;
    const int wm = (wave >> 1) * 64, wn = (wave & 1) * 64;
    f32x4 acc[4][4] = {};
    for (int k0 = 0; k0 < K; k0 += 64) {
#pragma unroll
        for (int it = 0; it < 4; ++it) {
            int c = it * 256 + wave * 64 + lane;
            int r = c >> 3, s = c & 7;
            int sd = ((s ^ (r & 7)) << 3);   // inverse-swizzled source slot
            gload_lds16(A + (size_t)(m0 + r) * K + k0 + sd,
                        &lA[(size_t)(it * 256 + wave * 64) * 8]);
            gload_lds16(Bt + (size_t)(n0 + r) * K + k0 + sd,
                        &lB[(size_t)(it * 256 + wave * 64) * 8]);
        }
        __syncthreads();   // drains vmcnt(0), then barrier
#pragma unroll
        for (int kk = 0; kk < 2; ++kk) {
            bf16x8 af[4], bf[4];
#pragma unroll
            for (int mi = 0; mi < 4; ++mi) {
                int row = wm + mi * 16 + l15;
                af[mi] = *(const bf16x8*)(&lA[row * 64 + (((kk * 4 + l4) ^ (row & 7)) << 3)]);
            }
#pragma unroll
            for (int ni = 0; ni < 4; ++ni) {
                int row = wn + ni * 16 + l15;
                bf[ni] = *(const bf16x8*)(&lB[row * 64 + (((kk * 4 + l4) ^ (row & 7)) << 3)]);
            }
#pragma unroll
            for (int mi = 0; mi < 4; ++mi)
#pragma unroll
                for (int ni = 0; ni < 4; ++ni)
                    acc[mi][ni] = mfma16(af[mi], bf[ni], acc[mi][ni]);
        }
        __syncthreads();
    }
#pragma unroll
    for (int mi = 0; mi < 4; ++mi)
#pragma unroll
        for (int ni = 0; ni < 4; ++ni)
#pragma unroll
            for (int i = 0; i < 4; ++i) {
                int r = m0 + wm + mi * 16 + l4 * 4 + i;
                int cc = n0 + wn + ni * 16 + l15;
                if constexpr (BF16OUT)
                    ((u16*)Cv)[(size_t)r * N + cc] = f2bf(acc[mi][ni][i]);
                else
                    ((float*)Cv)[(size_t)r * N + cc] = acc[mi][ni][i];
            }
}

// ---------- sin/cos table: tab[0..65535]=cos(t,d), tab[65536..]=sin ----------
__global__ void rope_tab(float* __restrict__ tab) {
    int i = blockIdx.x * 256 + threadIdx.x;   // 65536 = 2048 t x 32 d
    int t = i >> 5, d = i & 31;
    float invf = powf(10000.0f, -(float)d / 32.0f);
    float ang = (float)t * invf;
    tab[i] = cosf(ang);
    tab[i + 65536] = sinf(ang);
}

__device__ __forceinline__ void load64bf(const u16* p, float* v) {
#pragma unroll
    for (int j = 0; j < 8; ++j) {
        uint4 w = *(const uint4*)(p + j * 8);
        unsigned ws[4] = { w.x, w.y, w.z, w.w };
#pragma unroll
        for (int t = 0; t < 4; ++t) {
            union { unsigned u; float f; } a, b;
            a.u = (ws[t] & 0xFFFFu) << 16;
            b.u = ws[t] & 0xFFFF0000u;
            v[j * 8 + 2 * t] = a.f;
            v[j * 8 + 2 * t + 1] = b.f;
        }
    }
}

// ---------- RoPE + pack: C1[4096][3072] bf16 -> qb,kb (B,H,T,Dh) bf16, vt (B,H,Dh,T) bf16 ----------
__global__ void rope_pack(const u16* __restrict__ C1, const float* __restrict__ tab,
                          u16* __restrict__ qb, u16* __restrict__ kb, u16* __restrict__ vt) {
    int g = blockIdx.x * 256 + threadIdx.x;   // 65536
    int bh = g >> 11;
    int tq = g & 2047;
    int b = bh >> 4, h = bh & 15;
    const u16* base = C1 + (size_t)(b * 2048 + tq) * 3072 + h * 64;

    float cs[32], sn[32];
    const float* tc = tab + tq * 32;
    const float* ts = tab + 65536 + tq * 32;
#pragma unroll
    for (int j = 0; j < 8; ++j) {
        *(float4*)(&cs[j * 4]) = *(const float4*)(tc + j * 4);
        *(float4*)(&sn[j * 4]) = *(const float4*)(ts + j * 4);
    }
    float v[64];
    // ---- q ----
    load64bf(base, v);
#pragma unroll
    for (int d = 0; d < 32; ++d) {
        float a = v[d], bb = v[d + 32];
        v[d] = a * cs[d] - bb * sn[d];
        v[d + 32] = bb * cs[d] + a * sn[d];
    }
    {
        u16* dst = qb + ((size_t)bh * 2048 + tq) * 64;
#pragma unroll
        for (int j = 0; j < 8; ++j) {
            uint4 pk;
            pk.x = pack2(v[j * 8 + 0], v[j * 8 + 1]);
            pk.y = pack2(v[j * 8 + 2], v[j * 8 + 3]);
            pk.z = pack2(v[j * 8 + 4], v[j * 8 + 5]);
            pk.w = pack2(v[j * 8 + 6], v[j * 8 + 7]);
            *(uint4*)(dst + j * 8) = pk;
        }
    }
    // ---- k ----
    load64bf(base + 1024, v);
#pragma unroll
    for (int d = 0; d < 32; ++d) {
        float a = v[d], bb = v[d + 32];
        v[d] = a * cs[d] - bb * sn[d];
        v[d + 32] = bb * cs[d] + a * sn[d];
    }
    {
        u16* dst = kb + ((size_t)bh * 2048 + tq) * 64;
#pragma unroll
        for (int j = 0; j < 8; ++j) {
            uint4 pk;
            pk.x = pack2(v[j * 8 + 0], v[j * 8 + 1]);
            pk.y = pack2(v[j * 8 + 2], v[j * 8 + 3]);
            pk.z = pack2(v[j * 8 + 4], v[j * 8 + 5]);
            pk.w = pack2(v[j * 8 + 6], v[j * 8 + 7]);
            *(uint4*)(dst + j * 8) = pk;
        }
    }
    // ---- v (transposed store: vt[bh][dh][t]) ----
    load64bf(base + 2048, v);
#pragma unroll
    for (int d = 0; d < 64; ++d)
        vt[((size_t)bh * 64 + d) * 2048 + tq] = f2bf(v[d]);
}

// ---------- causal flash attention, paired q-tiles, swapped-QK, P-in-register ----------
// (R2-proven flash2, verbatim)
__global__ __launch_bounds__(256) void flash2(const u16* __restrict__ qb,
                                              const u16* __restrict__ kb,
                                              const u16* __restrict__ vt,
                                              u16* __restrict__ ao) {
    __shared__ u16 lK[2][64 * 64];   // [kv][d], XOR-swizzled 16B slots
    __shared__ u16 lV[2][64 * 64];   // [d][kv], XOR-swizzled 16B slots
    const int bh = blockIdx.y;
    const int b = bh >> 4, h = bh & 15;
    const int qtA = blockIdx.x;        // 0..15
    const int qtB = 31 - blockIdx.x;   // 16..31
    const int tid = threadIdx.x;
    const int wave = tid >> 6, lane = tid & 63;
    const int l15 = lane & 15, l4 = lane >> 4;
    const u16* qptr = qb + (size_t)bh * 2048 * 64;
    const u16* kptr = kb + (size_t)bh * 2048 * 64;
    const u16* vptr = vt + (size_t)bh * 64 * 2048;

    // Q fragments (B-operand: col=l15=q, k=l4*8+j=d)
    const int qrA = qtA * 64 + wave * 16 + l15;
    const int qrB = qtB * 64 + wave * 16 + l15;
    bf16x8 qA0 = *(const bf16x8*)(qptr + (size_t)qrA * 64 + l4 * 8);
    bf16x8 qA1 = *(const bf16x8*)(qptr + (size_t)qrA * 64 + 32 + l4 * 8);
    bf16x8 qB0 = *(const bf16x8*)(qptr + (size_t)qrB * 64 + l4 * 8);
    bf16x8 qB1 = *(const bf16x8*)(qptr + (size_t)qrB * 64 + 32 + l4 * 8);

    f32x4 OA[4] = {}, OB[4] = {};
    float mA = -INFINITY, lA = 0.f, mB = -INFINITY, lB = 0.f;

    int idxO[4], idxEx[4];
#pragma unroll
    for (int i = 0; i < 4; ++i) idxO[i] = (lane & 48) | (l4 * 4 + i);
#pragma unroll
    for (int r = 0; r < 4; ++r) idxEx[r] = (((2 * l4 + (r >> 1)) & 3) << 4) | l15;

    auto stage = [&](int buf, int kv0) {
#pragma unroll
        for (int it = 0; it < 2; ++it) {
            int cb = wave * 64 + it * 256;       // wave-uniform chunk base
            int c = cb + lane;                   // chunk 0..511
            int r = c >> 3, s = c & 7;
            int sd = (s ^ (r & 7)) * 8;          // inverse-swizzled source slot
            gload_lds16(kptr + (size_t)(kv0 + r) * 64 + sd, &lK[buf][cb * 8]);
            gload_lds16(vptr + (size_t)r * 2048 + kv0 + sd, &lV[buf][cb * 8]);
        }
    };
    auto ldK = [&](int buf, int row, int slot) -> bf16x8 {
        return *(const bf16x8*)(&lK[buf][row * 64 + ((slot ^ (row & 7)) << 3)]);
    };
    auto ldV = [&](int buf, int row, int slot) -> bf16x8 {
        return *(const bf16x8*)(&lV[buf][row * 64 + ((slot ^ (row & 7)) << 3)]);
    };

    // softmax + pack-to-A-frag for one tile (P^T in regs: q=l15, kv=c*16+l4*4+i)
    auto smpack = [&](f32x4 S[4], float& mrun, float& lrun, f32x4 O[4],
                      bf16x8 af[2], bool diag, int kv0, int qrow) {
        float p[4][4];
#pragma unroll
        for (int c = 0; c < 4; ++c)
#pragma unroll
            for (int i = 0; i < 4; ++i) {
                float s = S[c][i] * 0.125f;
                if (diag && (kv0 + c * 16 + l4 * 4 + i > qrow)) s = -INFINITY;
                p[c][i] = s;
            }
        float m = p[0][0];
#pragma unroll
        for (int c = 0; c < 4; ++c)
#pragma unroll
            for (int i = 0; i < 4; ++i) m = fmaxf(m, p[c][i]);
        m = fmaxf(m, __shfl_xor(m, 16));
        m = fmaxf(m, __shfl_xor(m, 32));
        float mnew = fmaxf(mrun, m);
        float corr = __expf(mrun - mnew);
        float rs = 0.f;
#pragma unroll
        for (int c = 0; c < 4; ++c)
#pragma unroll
            for (int i = 0; i < 4; ++i) { p[c][i] = __expf(p[c][i] - mnew); rs += p[c][i]; }
        rs += __shfl_xor(rs, 16);
        rs += __shfl_xor(rs, 32);
        lrun = lrun * corr + rs;
        mrun = mnew;
#pragma unroll
        for (int i = 0; i < 4; ++i) {
            float cf = __shfl(corr, idxO[i]);
#pragma unroll
            for (int c2 = 0; c2 < 4; ++c2) O[c2][i] *= cf;
        }
        unsigned w[4][2];
#pragma unroll
        for (int c = 0; c < 4; ++c) {
            asm("v_cvt_pk_bf16_f32 %0, %1, %2" : "=v"(w[c][0]) : "v"(p[c][0]), "v"(p[c][1]));
            asm("v_cvt_pk_bf16_f32 %0, %1, %2" : "=v"(w[c][1]) : "v"(p[c][2]), "v"(p[c][3]));
        }
#pragma unroll
        for (int ks = 0; ks < 2; ++ks) {
            unsigned a0, a1, a2, a3;
            {
                unsigned lo = __shfl((int)w[2 * ks][0], idxEx[0]);
                unsigned hi = __shfl((int)w[2 * ks + 1][0], idxEx[0]);
                a0 = (l4 < 2) ? lo : hi;
            }
            {
                unsigned lo = __shfl((int)w[2 * ks][1], idxEx[1]);
                unsigned hi = __shfl((int)w[2 * ks + 1][1], idxEx[1]);
                a1 = (l4 < 2) ? lo : hi;
            }
            {
                unsigned lo = __shfl((int)w[2 * ks][0], idxEx[2]);
                unsigned hi = __shfl((int)w[2 * ks + 1][0], idxEx[2]);
                a2 = (l4 < 2) ? lo : hi;
            }
            {
                unsigned lo = __shfl((int)w[2 * ks][1], idxEx[3]);
                unsigned hi = __shfl((int)w[2 * ks + 1][1], idxEx[3]);
                a3 = (l4 < 2) ? lo : hi;
            }
            union { unsigned u[4]; bf16x8 v; } cvt;
            cvt.u[0] = a0; cvt.u[1] = a1; cvt.u[2] = a2; cvt.u[3] = a3;
            af[ks] = cvt.v;
        }
    };

    stage(0, 0);
    for (int kvb = 0; kvb <= qtB; ++kvb) {
        const int cur = kvb & 1;
        const int kv0 = kvb * 64;
        const bool doA = (kvb <= qtA);
        if (kvb < qtB) {
            stage(cur ^ 1, kv0 + 64);
            asm volatile("s_waitcnt vmcnt(4)" ::: "memory");
        } else {
            asm volatile("s_waitcnt vmcnt(0)" ::: "memory");
        }
        __builtin_amdgcn_s_barrier();
        __builtin_amdgcn_sched_barrier(0);

        // QK^T swapped: S'[kv][q] — K/V fragment reads shared by both tiles
        f32x4 SA[4] = {}, SB[4] = {};
#pragma unroll
        for (int c = 0; c < 4; ++c) {
            bf16x8 kf0 = ldK(cur, c * 16 + l15, l4);
            bf16x8 kf1 = ldK(cur, c * 16 + l15, 4 + l4);
            SB[c] = mfma16(kf0, qB0, SB[c]);
            SB[c] = mfma16(kf1, qB1, SB[c]);
            if (doA) {
                SA[c] = mfma16(kf0, qA0, SA[c]);
                SA[c] = mfma16(kf1, qA1, SA[c]);
            }
        }
        bf16x8 aB[2], aA[2];
        smpack(SB, mB, lB, OB, aB, kvb == qtB, kv0, qrB);
        if (doA) smpack(SA, mA, lA, OA, aA, kvb == qtA, kv0, qrA);
#pragma unroll
        for (int ks = 0; ks < 2; ++ks)
#pragma unroll
            for (int c2 = 0; c2 < 4; ++c2) {
                bf16x8 vf = ldV(cur, c2 * 16 + l15, ks * 4 + l4);
                OB[c2] = mfma16(aB[ks], vf, OB[c2]);
                if (doA) OA[c2] = mfma16(aA[ks], vf, OA[c2]);
            }
        __builtin_amdgcn_s_barrier();   // protect buffer overwrite by next stage
    }

    // epilogue: O rows are q'=l4*4+i, cols d=c2*16+l15
#pragma unroll
    for (int i = 0; i < 4; ++i) {
        float lbv = __shfl(lB, idxO[i]);
        float lav = __shfl(lA, idxO[i]);
        float rb = 1.f / lbv, ra = 1.f / lav;
        int qgB = qtB * 64 + wave * 16 + l4 * 4 + i;
        int qgA = qtA * 64 + wave * 16 + l4 * 4 + i;
#pragma unroll
        for (int c2 = 0; c2 < 4; ++c2) {
            ao[(size_t)(b * 2048 + qgB) * 1024 + h * 64 + c2 * 16 + l15] = f2bf(OB[c2][i] * rb);
            ao[(size_t)(b * 2048 + qgA) * 1024 + h * 64 + c2 * 16 + l15] = f2bf(OA[c2][i] * ra);
        }
    }
}

// ---------- launch ----------
extern "C" void kernel_launch(void* const* d_in, const int* in_sizes, int n_in,
                              void* d_out, int out_size, void* d_ws, size_t ws_size,
                              hipStream_t stream) {
    const float* x    = (const float*)d_in[0];   // (2,2048,1024)
    const float* Wqkv = (const float*)d_in[1];   // (1024,3072)
    const float* Wout = (const float*)d_in[2];   // (1024,1024)
    float* out = (float*)d_out;                  // (2,2048,1024)
    char* ws = (char*)d_ws;

    u16*   xb  = (u16*)(ws + 0);            // 8 MB  (4096x1024 bf16)
    u16*   Wtq = (u16*)(ws + 8388608);      // 6 MB  (3072x1024 bf16)
    u16*   Wto = (u16*)(ws + 14680064);     // 2 MB  (1024x1024 bf16)
    u16*   C1b = (u16*)(ws + 16777216);     // 24 MB (4096x3072 bf16)
    u16*   qb  = (u16*)(ws + 67108864);     // 8 MB  (B,H,T,Dh bf16)
    u16*   kb  = (u16*)(ws + 75497472);     // 8 MB
    u16*   vt  = (u16*)(ws + 83886080);     // 8 MB  (B,H,Dh,T bf16)
    float* tab = (float*)(ws + 92274688);   // 512 KB sin/cos table
    u16*   ao  = (u16*)(ws + 0);            // reuse xb region (GEMM1 done by then)

    cvt_bf16<<<dim3(4096), dim3(256), 0, stream>>>(x, xb);
    transpose_cvt<<<dim3(96, 32), dim3(256), 0, stream>>>(Wqkv, Wtq, 1024, 3072);
    transpose_cvt<<<dim3(32, 32), dim3(256), 0, stream>>>(Wout, Wto, 1024, 1024);
    rope_tab<<<dim3(256), dim3(256), 0, stream>>>(tab);
    gemm_bt<true><<<dim3(24, 32), dim3(256), 0, stream>>>(xb, Wtq, (void*)C1b, 4096, 3072, 1024);
    rope_pack<<<dim3(256), dim3(256), 0, stream>>>(C1b, tab, qb, kb, vt);
    flash2<<<dim3(16, 32), dim3(256), 0, stream>>>(qb, kb, vt, ao);
    gemm_bt<false><<<dim3(8, 32), dim3(256), 0, stream>>>(ao, Wto, (void*)out, 4096, 1024, 1024);
}

// Round 7
// 168.779 us; speedup vs baseline: 1.6507x; 1.0084x over previous
//
#include <hip/hip_runtime.h>
#include <math.h>

typedef unsigned short u16;
typedef short bf16x8 __attribute__((ext_vector_type(8)));
typedef float f32x4 __attribute__((ext_vector_type(4)));

// ---------- helpers ----------
__device__ __forceinline__ u16 f2bf(float f) {
    union { float f; unsigned u; } x; x.f = f;
    unsigned u = x.u;
    unsigned r = (u + 0x7fffu + ((u >> 16) & 1u)) >> 16;   // RNE, no NaN in data
    return (u16)r;
}
__device__ __forceinline__ unsigned pack2(float a, float b) {
    return (unsigned)f2bf(a) | ((unsigned)f2bf(b) << 16);
}
__device__ __forceinline__ f32x4 mfma16(bf16x8 a, bf16x8 b, f32x4 c) {
    return __builtin_amdgcn_mfma_f32_16x16x32_bf16(a, b, c, 0, 0, 0);
}
__device__ __forceinline__ void gload_lds16(const void* g, void* l) {
    __builtin_amdgcn_global_load_lds((const __attribute__((address_space(1))) void*)g,
                                     (__attribute__((address_space(3))) void*)l,
                                     16, 0, 0);
}

// ---------- fp32 -> bf16 cast (vectorized) ----------
__global__ void cvt_bf16(const float* __restrict__ X, u16* __restrict__ Y) {
    int i = (blockIdx.x * 256 + threadIdx.x) * 4;
    float4 v = *(const float4*)(X + i);
    uint2 o;
    o.x = pack2(v.x, v.y);
    o.y = pack2(v.z, v.w);
    *(uint2*)(Y + i) = o;
}

// ---------- W[R][C] fp32 -> Wt[C][R] bf16 (LDS-tiled transpose) ----------
__global__ void transpose_cvt(const float* __restrict__ W, u16* __restrict__ Wt,
                              int R, int C) {
    __shared__ u16 tile[32][33];
    int tx = threadIdx.x & 31, ty = threadIdx.x >> 5;  // 32 x 8
    int bx = blockIdx.x * 32;
    int by = blockIdx.y * 32;
#pragma unroll
    for (int r = ty; r < 32; r += 8)
        tile[r][tx] = f2bf(W[(size_t)(by + r) * C + bx + tx]);
    __syncthreads();
#pragma unroll
    for (int r = ty; r < 32; r += 8)
        Wt[(size_t)(bx + r) * R + by + tx] = tile[tx][r];
}

// ---------- GEMM: C[M][N] = A[M][K] * Bt[N][K]^T, BK=64, XOR-swizzled LDS ----------
template <bool BF16OUT>
__global__ __launch_bounds__(256) void gemm_bt(const u16* __restrict__ A,
                                               const u16* __restrict__ Bt,
                                               void* __restrict__ Cv,
                                               int M, int N, int K) {
    __shared__ u16 lA[128 * 64];
    __shared__ u16 lB[128 * 64];
    const int tid = threadIdx.x;
    const int wave = tid >> 6, lane = tid & 63;
    const int l15 = lane & 15, l4 = lane >> 4;
    const int m0 = blockIdx.y * 128, n0 = blockIdx.x * 128;
    const int wm = (wave >> 1) * 64, wn = (wave & 1) * 64;
    f32x4 acc[4][4] = {};
    for (int k0 = 0; k0 < K; k0 += 64) {
#pragma unroll
        for (int it = 0; it < 4; ++it) {
            int c = it * 256 + wave * 64 + lane;
            int r = c >> 3, s = c & 7;
            int sd = ((s ^ (r & 7)) << 3);   // inverse-swizzled source slot
            gload_lds16(A + (size_t)(m0 + r) * K + k0 + sd,
                        &lA[(size_t)(it * 256 + wave * 64) * 8]);
            gload_lds16(Bt + (size_t)(n0 + r) * K + k0 + sd,
                        &lB[(size_t)(it * 256 + wave * 64) * 8]);
        }
        __syncthreads();   // drains vmcnt(0), then barrier
#pragma unroll
        for (int kk = 0; kk < 2; ++kk) {
            bf16x8 af[4], bf[4];
#pragma unroll
            for (int mi = 0; mi < 4; ++mi) {
                int row = wm + mi * 16 + l15;
                af[mi] = *(const bf16x8*)(&lA[row * 64 + (((kk * 4 + l4) ^ (row & 7)) << 3)]);
            }
#pragma unroll
            for (int ni = 0; ni < 4; ++ni) {
                int row = wn + ni * 16 + l15;
                bf[ni] = *(const bf16x8*)(&lB[row * 64 + (((kk * 4 + l4) ^ (row & 7)) << 3)]);
            }
#pragma unroll
            for (int mi = 0; mi < 4; ++mi)
#pragma unroll
                for (int ni = 0; ni < 4; ++ni)
                    acc[mi][ni] = mfma16(af[mi], bf[ni], acc[mi][ni]);
        }
        __syncthreads();
    }
#pragma unroll
    for (int mi = 0; mi < 4; ++mi)
#pragma unroll
        for (int ni = 0; ni < 4; ++ni)
#pragma unroll
            for (int i = 0; i < 4; ++i) {
                int r = m0 + wm + mi * 16 + l4 * 4 + i;
                int cc = n0 + wn + ni * 16 + l15;
                if constexpr (BF16OUT)
                    ((u16*)Cv)[(size_t)r * N + cc] = f2bf(acc[mi][ni][i]);
                else
                    ((float*)Cv)[(size_t)r * N + cc] = acc[mi][ni][i];
            }
}

// ---------- sin/cos table: tab[0..65535]=cos(t,d), tab[65536..]=sin ----------
__global__ void rope_tab(float* __restrict__ tab) {
    int i = blockIdx.x * 256 + threadIdx.x;   // 65536 = 2048 t x 32 d
    int t = i >> 5, d = i & 31;
    float invf = powf(10000.0f, -(float)d / 32.0f);
    float ang = (float)t * invf;
    tab[i] = cosf(ang);
    tab[i + 65536] = sinf(ang);
}

__device__ __forceinline__ void load64bf(const u16* p, float* v) {
#pragma unroll
    for (int j = 0; j < 8; ++j) {
        uint4 w = *(const uint4*)(p + j * 8);
        unsigned ws[4] = { w.x, w.y, w.z, w.w };
#pragma unroll
        for (int t = 0; t < 4; ++t) {
            union { unsigned u; float f; } a, b;
            a.u = (ws[t] & 0xFFFFu) << 16;
            b.u = ws[t] & 0xFFFF0000u;
            v[j * 8 + 2 * t] = a.f;
            v[j * 8 + 2 * t + 1] = b.f;
        }
    }
}

// ---------- RoPE + pack: C1[4096][3072] bf16 -> qb (pre-scaled), kb, vt ----------
// q is pre-scaled by 0.125*log2(e) so flash softmax runs in exp2 domain.
__global__ void rope_pack(const u16* __restrict__ C1, const float* __restrict__ tab,
                          u16* __restrict__ qb, u16* __restrict__ kb, u16* __restrict__ vt) {
    const float SC = 0.18033688011112042f;   // 0.125 * log2(e)
    int g = blockIdx.x * 256 + threadIdx.x;   // 65536
    int bh = g >> 11;
    int tq = g & 2047;
    int b = bh >> 4, h = bh & 15;
    const u16* base = C1 + (size_t)(b * 2048 + tq) * 3072 + h * 64;

    float cs[32], sn[32];
    const float* tc = tab + tq * 32;
    const float* ts = tab + 65536 + tq * 32;
#pragma unroll
    for (int j = 0; j < 8; ++j) {
        *(float4*)(&cs[j * 4]) = *(const float4*)(tc + j * 4);
        *(float4*)(&sn[j * 4]) = *(const float4*)(ts + j * 4);
    }
    float v[64];
    // ---- q (scaled) ----
    load64bf(base, v);
#pragma unroll
    for (int d = 0; d < 32; ++d) {
        float a = v[d], bb = v[d + 32];
        v[d] = (a * cs[d] - bb * sn[d]) * SC;
        v[d + 32] = (bb * cs[d] + a * sn[d]) * SC;
    }
    {
        u16* dst = qb + ((size_t)bh * 2048 + tq) * 64;
#pragma unroll
        for (int j = 0; j < 8; ++j) {
            uint4 pk;
            pk.x = pack2(v[j * 8 + 0], v[j * 8 + 1]);
            pk.y = pack2(v[j * 8 + 2], v[j * 8 + 3]);
            pk.z = pack2(v[j * 8 + 4], v[j * 8 + 5]);
            pk.w = pack2(v[j * 8 + 6], v[j * 8 + 7]);
            *(uint4*)(dst + j * 8) = pk;
        }
    }
    // ---- k ----
    load64bf(base + 1024, v);
#pragma unroll
    for (int d = 0; d < 32; ++d) {
        float a = v[d], bb = v[d + 32];
        v[d] = a * cs[d] - bb * sn[d];
        v[d + 32] = bb * cs[d] + a * sn[d];
    }
    {
        u16* dst = kb + ((size_t)bh * 2048 + tq) * 64;
#pragma unroll
        for (int j = 0; j < 8; ++j) {
            uint4 pk;
            pk.x = pack2(v[j * 8 + 0], v[j * 8 + 1]);
            pk.y = pack2(v[j * 8 + 2], v[j * 8 + 3]);
            pk.z = pack2(v[j * 8 + 4], v[j * 8 + 5]);
            pk.w = pack2(v[j * 8 + 6], v[j * 8 + 7]);
            *(uint4*)(dst + j * 8) = pk;
        }
    }
    // ---- v (transposed store: vt[bh][dh][t]) ----
    load64bf(base + 2048, v);
#pragma unroll
    for (int d = 0; d < 64; ++d)
        vt[((size_t)bh * 64 + d) * 2048 + tq] = f2bf(v[d]);
}

// ---------- causal flash attention: R4-proven flash2, ONLY change = exp2 domain ----------
// (q pre-scaled by 0.125*log2e; __expf -> exp2f; no 0.125 mul. All else verbatim.)
__global__ __launch_bounds__(256) void flash2e(const u16* __restrict__ qb,
                                               const u16* __restrict__ kb,
                                               const u16* __restrict__ vt,
                                               u16* __restrict__ ao) {
    __shared__ u16 lK[2][64 * 64];   // [kv][d], XOR-swizzled 16B slots
    __shared__ u16 lV[2][64 * 64];   // [d][kv], XOR-swizzled 16B slots
    const int bh = blockIdx.y;
    const int b = bh >> 4, h = bh & 15;
    const int qtA = blockIdx.x;        // 0..15
    const int qtB = 31 - blockIdx.x;   // 16..31
    const int tid = threadIdx.x;
    const int wave = tid >> 6, lane = tid & 63;
    const int l15 = lane & 15, l4 = lane >> 4;
    const u16* qptr = qb + (size_t)bh * 2048 * 64;
    const u16* kptr = kb + (size_t)bh * 2048 * 64;
    const u16* vptr = vt + (size_t)bh * 64 * 2048;

    // Q fragments (B-operand: col=l15=q, k=l4*8+j=d)
    const int qrA = qtA * 64 + wave * 16 + l15;
    const int qrB = qtB * 64 + wave * 16 + l15;
    bf16x8 qA0 = *(const bf16x8*)(qptr + (size_t)qrA * 64 + l4 * 8);
    bf16x8 qA1 = *(const bf16x8*)(qptr + (size_t)qrA * 64 + 32 + l4 * 8);
    bf16x8 qB0 = *(const bf16x8*)(qptr + (size_t)qrB * 64 + l4 * 8);
    bf16x8 qB1 = *(const bf16x8*)(qptr + (size_t)qrB * 64 + 32 + l4 * 8);

    f32x4 OA[4] = {}, OB[4] = {};
    float mA = -INFINITY, lA = 0.f, mB = -INFINITY, lB = 0.f;

    int idxO[4], idxEx[4];
#pragma unroll
    for (int i = 0; i < 4; ++i) idxO[i] = (lane & 48) | (l4 * 4 + i);
#pragma unroll
    for (int r = 0; r < 4; ++r) idxEx[r] = (((2 * l4 + (r >> 1)) & 3) << 4) | l15;

    auto stage = [&](int buf, int kv0) {
#pragma unroll
        for (int it = 0; it < 2; ++it) {
            int cb = wave * 64 + it * 256;       // wave-uniform chunk base
            int c = cb + lane;                   // chunk 0..511
            int r = c >> 3, s = c & 7;
            int sd = (s ^ (r & 7)) * 8;          // inverse-swizzled source slot
            gload_lds16(kptr + (size_t)(kv0 + r) * 64 + sd, &lK[buf][cb * 8]);
            gload_lds16(vptr + (size_t)r * 2048 + kv0 + sd, &lV[buf][cb * 8]);
        }
    };
    auto ldK = [&](int buf, int row, int slot) -> bf16x8 {
        return *(const bf16x8*)(&lK[buf][row * 64 + ((slot ^ (row & 7)) << 3)]);
    };
    auto ldV = [&](int buf, int row, int slot) -> bf16x8 {
        return *(const bf16x8*)(&lV[buf][row * 64 + ((slot ^ (row & 7)) << 3)]);
    };

    // softmax + pack-to-A-frag for one tile (P^T in regs: q=l15, kv=c*16+l4*4+i)
    auto smpack = [&](f32x4 S[4], float& mrun, float& lrun, f32x4 O[4],
                      bf16x8 af[2], bool diag, int kv0, int qrow) {
        float p[4][4];
#pragma unroll
        for (int c = 0; c < 4; ++c)
#pragma unroll
            for (int i = 0; i < 4; ++i) {
                float s = S[c][i];
                if (diag && (kv0 + c * 16 + l4 * 4 + i > qrow)) s = -INFINITY;
                p[c][i] = s;
            }
        float m = p[0][0];
#pragma unroll
        for (int c = 0; c < 4; ++c)
#pragma unroll
            for (int i = 0; i < 4; ++i) m = fmaxf(m, p[c][i]);
        m = fmaxf(m, __shfl_xor(m, 16));
        m = fmaxf(m, __shfl_xor(m, 32));
        float mnew = fmaxf(mrun, m);
        float corr = __builtin_amdgcn_exp2f(mrun - mnew);
        float rs = 0.f;
#pragma unroll
        for (int c = 0; c < 4; ++c)
#pragma unroll
            for (int i = 0; i < 4; ++i) { p[c][i] = __builtin_amdgcn_exp2f(p[c][i] - mnew); rs += p[c][i]; }
        rs += __shfl_xor(rs, 16);
        rs += __shfl_xor(rs, 32);
        lrun = lrun * corr + rs;
        mrun = mnew;
#pragma unroll
        for (int i = 0; i < 4; ++i) {
            float cf = __shfl(corr, idxO[i]);
#pragma unroll
            for (int c2 = 0; c2 < 4; ++c2) O[c2][i] *= cf;
        }
        unsigned w[4][2];
#pragma unroll
        for (int c = 0; c < 4; ++c) {
            asm("v_cvt_pk_bf16_f32 %0, %1, %2" : "=v"(w[c][0]) : "v"(p[c][0]), "v"(p[c][1]));
            asm("v_cvt_pk_bf16_f32 %0, %1, %2" : "=v"(w[c][1]) : "v"(p[c][2]), "v"(p[c][3]));
        }
#pragma unroll
        for (int ks = 0; ks < 2; ++ks) {
            unsigned a0, a1, a2, a3;
            {
                unsigned lo = __shfl((int)w[2 * ks][0], idxEx[0]);
                unsigned hi = __shfl((int)w[2 * ks + 1][0], idxEx[0]);
                a0 = (l4 < 2) ? lo : hi;
            }
            {
                unsigned lo = __shfl((int)w[2 * ks][1], idxEx[1]);
                unsigned hi = __shfl((int)w[2 * ks + 1][1], idxEx[1]);
                a1 = (l4 < 2) ? lo : hi;
            }
            {
                unsigned lo = __shfl((int)w[2 * ks][0], idxEx[2]);
                unsigned hi = __shfl((int)w[2 * ks + 1][0], idxEx[2]);
                a2 = (l4 < 2) ? lo : hi;
            }
            {
                unsigned lo = __shfl((int)w[2 * ks][1], idxEx[3]);
                unsigned hi = __shfl((int)w[2 * ks + 1][1], idxEx[3]);
                a3 = (l4 < 2) ? lo : hi;
            }
            union { unsigned u[4]; bf16x8 v; } cvt;
            cvt.u[0] = a0; cvt.u[1] = a1; cvt.u[2] = a2; cvt.u[3] = a3;
            af[ks] = cvt.v;
        }
    };

    stage(0, 0);
    for (int kvb = 0; kvb <= qtB; ++kvb) {
        const int cur = kvb & 1;
        const int kv0 = kvb * 64;
        const bool doA = (kvb <= qtA);
        if (kvb < qtB) {
            stage(cur ^ 1, kv0 + 64);
            asm volatile("s_waitcnt vmcnt(4)" ::: "memory");
        } else {
            asm volatile("s_waitcnt vmcnt(0)" ::: "memory");
        }
        __builtin_amdgcn_s_barrier();
        __builtin_amdgcn_sched_barrier(0);

        // QK^T swapped: S'[kv][q] — K/V fragment reads shared by both tiles
        f32x4 SA[4] = {}, SB[4] = {};
#pragma unroll
        for (int c = 0; c < 4; ++c) {
            bf16x8 kf0 = ldK(cur, c * 16 + l15, l4);
            bf16x8 kf1 = ldK(cur, c * 16 + l15, 4 + l4);
            SB[c] = mfma16(kf0, qB0, SB[c]);
            SB[c] = mfma16(kf1, qB1, SB[c]);
            if (doA) {
                SA[c] = mfma16(kf0, qA0, SA[c]);
                SA[c] = mfma16(kf1, qA1, SA[c]);
            }
        }
        bf16x8 aB[2], aA[2];
        smpack(SB, mB, lB, OB, aB, kvb == qtB, kv0, qrB);
        if (doA) smpack(SA, mA, lA, OA, aA, kvb == qtA, kv0, qrA);
#pragma unroll
        for (int ks = 0; ks < 2; ++ks)
#pragma unroll
            for (int c2 = 0; c2 < 4; ++c2) {
                bf16x8 vf = ldV(cur, c2 * 16 + l15, ks * 4 + l4);
                OB[c2] = mfma16(aB[ks], vf, OB[c2]);
                if (doA) OA[c2] = mfma16(aA[ks], vf, OA[c2]);
            }
        __builtin_amdgcn_s_barrier();   // protect buffer overwrite by next stage
    }

    // epilogue: O rows are q'=l4*4+i, cols d=c2*16+l15
#pragma unroll
    for (int i = 0; i < 4; ++i) {
        float lbv = __shfl(lB, idxO[i]);
        float lav = __shfl(lA, idxO[i]);
        float rb = 1.f / lbv, ra = 1.f / lav;
        int qgB = qtB * 64 + wave * 16 + l4 * 4 + i;
        int qgA = qtA * 64 + wave * 16 + l4 * 4 + i;
#pragma unroll
        for (int c2 = 0; c2 < 4; ++c2) {
            ao[(size_t)(b * 2048 + qgB) * 1024 + h * 64 + c2 * 16 + l15] = f2bf(OB[c2][i] * rb);
            ao[(size_t)(b * 2048 + qgA) * 1024 + h * 64 + c2 * 16 + l15] = f2bf(OA[c2][i] * ra);
        }
    }
}

// ---------- launch ----------
extern "C" void kernel_launch(void* const* d_in, const int* in_sizes, int n_in,
                              void* d_out, int out_size, void* d_ws, size_t ws_size,
                              hipStream_t stream) {
    const float* x    = (const float*)d_in[0];   // (2,2048,1024)
    const float* Wqkv = (const float*)d_in[1];   // (1024,3072)
    const float* Wout = (const float*)d_in[2];   // (1024,1024)
    float* out = (float*)d_out;                  // (2,2048,1024)
    char* ws = (char*)d_ws;

    u16*   xb  = (u16*)(ws + 0);            // 8 MB  (4096x1024 bf16)
    u16*   Wtq = (u16*)(ws + 8388608);      // 6 MB  (3072x1024 bf16)
    u16*   Wto = (u16*)(ws + 14680064);     // 2 MB  (1024x1024 bf16)
    u16*   C1b = (u16*)(ws + 16777216);     // 24 MB (4096x3072 bf16)
    u16*   qb  = (u16*)(ws + 67108864);     // 8 MB  (B,H,T,Dh bf16, pre-scaled)
    u16*   kb  = (u16*)(ws + 75497472);     // 8 MB
    u16*   vt  = (u16*)(ws + 83886080);     // 8 MB  (B,H,Dh,T bf16)
    float* tab = (float*)(ws + 92274688);   // 512 KB sin/cos table
    u16*   ao  = (u16*)(ws + 0);            // reuse xb region (GEMM1 done by then)

    cvt_bf16<<<dim3(4096), dim3(256), 0, stream>>>(x, xb);
    transpose_cvt<<<dim3(96, 32), dim3(256), 0, stream>>>(Wqkv, Wtq, 1024, 3072);
    transpose_cvt<<<dim3(32, 32), dim3(256), 0, stream>>>(Wout, Wto, 1024, 1024);
    rope_tab<<<dim3(256), dim3(256), 0, stream>>>(tab);
    gemm_bt<true><<<dim3(24, 32), dim3(256), 0, stream>>>(xb, Wtq, (void*)C1b, 4096, 3072, 1024);
    rope_pack<<<dim3(256), dim3(256), 0, stream>>>(C1b, tab, qb, kb, vt);
    flash2e<<<dim3(16, 32), dim3(256), 0, stream>>>(qb, kb, vt, ao);
    gemm_bt<false><<<dim3(8, 32), dim3(256), 0, stream>>>(ao, Wto, (void*)out, 4096, 1024, 1024);
}

// Round 8
// 153.155 us; speedup vs baseline: 1.8191x; 1.1020x over previous
//
#include <hip/hip_runtime.h>
#include <math.h>

typedef unsigned short u16;
typedef short bf16x8 __attribute__((ext_vector_type(8)));
typedef float f32x4 __attribute__((ext_vector_type(4)));

// ---------- helpers ----------
__device__ __forceinline__ u16 f2bf(float f) {
    union { float f; unsigned u; } x; x.f = f;
    unsigned u = x.u;
    unsigned r = (u + 0x7fffu + ((u >> 16) & 1u)) >> 16;   // RNE, no NaN in data
    return (u16)r;
}
__device__ __forceinline__ unsigned pack2(float a, float b) {
    return (unsigned)f2bf(a) | ((unsigned)f2bf(b) << 16);
}
__device__ __forceinline__ f32x4 mfma16(bf16x8 a, bf16x8 b, f32x4 c) {
    return __builtin_amdgcn_mfma_f32_16x16x32_bf16(a, b, c, 0, 0, 0);
}
__device__ __forceinline__ void gload_lds16(const void* g, void* l) {
    __builtin_amdgcn_global_load_lds((const __attribute__((address_space(1))) void*)g,
                                     (__attribute__((address_space(3))) void*)l,
                                     16, 0, 0);
}

// ---------- fp32 -> bf16 cast (vectorized) ----------
__global__ void cvt_bf16(const float* __restrict__ X, u16* __restrict__ Y) {
    int i = (blockIdx.x * 256 + threadIdx.x) * 4;
    float4 v = *(const float4*)(X + i);
    uint2 o;
    o.x = pack2(v.x, v.y);
    o.y = pack2(v.z, v.w);
    *(uint2*)(Y + i) = o;
}

// ---------- W[R][C] fp32 -> Wt[C][R] bf16 (LDS-tiled transpose) ----------
__global__ void transpose_cvt(const float* __restrict__ W, u16* __restrict__ Wt,
                              int R, int C) {
    __shared__ u16 tile[32][33];
    int tx = threadIdx.x & 31, ty = threadIdx.x >> 5;  // 32 x 8
    int bx = blockIdx.x * 32;
    int by = blockIdx.y * 32;
#pragma unroll
    for (int r = ty; r < 32; r += 8)
        tile[r][tx] = f2bf(W[(size_t)(by + r) * C + bx + tx]);
    __syncthreads();
#pragma unroll
    for (int r = ty; r < 32; r += 8)
        Wt[(size_t)(bx + r) * R + by + tx] = tile[tx][r];
}

// ---------- GEMM: C[M][N] = A[M][K] * Bt[N][K]^T, BK=64, XOR-swizzled LDS ----------
template <bool BF16OUT>
__global__ __launch_bounds__(256) void gemm_bt(const u16* __restrict__ A,
                                               const u16* __restrict__ Bt,
                                               void* __restrict__ Cv,
                                               int M, int N, int K) {
    __shared__ u16 lA[128 * 64];
    __shared__ u16 lB[128 * 64];
    const int tid = threadIdx.x;
    const int wave = tid >> 6, lane = tid & 63;
    const int l15 = lane & 15, l4 = lane >> 4;
    const int m0 = blockIdx.y * 128, n0 = blockIdx.x * 128;
    const int wm = (wave >> 1) * 64, wn = (wave & 1) * 64;
    f32x4 acc[4][4] = {};
    for (int k0 = 0; k0 < K; k0 += 64) {
#pragma unroll
        for (int it = 0; it < 4; ++it) {
            int c = it * 256 + wave * 64 + lane;
            int r = c >> 3, s = c & 7;
            int sd = ((s ^ (r & 7)) << 3);   // inverse-swizzled source slot
            gload_lds16(A + (size_t)(m0 + r) * K + k0 + sd,
                        &lA[(size_t)(it * 256 + wave * 64) * 8]);
            gload_lds16(Bt + (size_t)(n0 + r) * K + k0 + sd,
                        &lB[(size_t)(it * 256 + wave * 64) * 8]);
        }
        __syncthreads();   // drains vmcnt(0), then barrier
#pragma unroll
        for (int kk = 0; kk < 2; ++kk) {
            bf16x8 af[4], bf[4];
#pragma unroll
            for (int mi = 0; mi < 4; ++mi) {
                int row = wm + mi * 16 + l15;
                af[mi] = *(const bf16x8*)(&lA[row * 64 + (((kk * 4 + l4) ^ (row & 7)) << 3)]);
            }
#pragma unroll
            for (int ni = 0; ni < 4; ++ni) {
                int row = wn + ni * 16 + l15;
                bf[ni] = *(const bf16x8*)(&lB[row * 64 + (((kk * 4 + l4) ^ (row & 7)) << 3)]);
            }
#pragma unroll
            for (int mi = 0; mi < 4; ++mi)
#pragma unroll
                for (int ni = 0; ni < 4; ++ni)
                    acc[mi][ni] = mfma16(af[mi], bf[ni], acc[mi][ni]);
        }
        __syncthreads();
    }
#pragma unroll
    for (int mi = 0; mi < 4; ++mi)
#pragma unroll
        for (int ni = 0; ni < 4; ++ni)
#pragma unroll
            for (int i = 0; i < 4; ++i) {
                int r = m0 + wm + mi * 16 + l4 * 4 + i;
                int cc = n0 + wn + ni * 16 + l15;
                if constexpr (BF16OUT)
                    ((u16*)Cv)[(size_t)r * N + cc] = f2bf(acc[mi][ni][i]);
                else
                    ((float*)Cv)[(size_t)r * N + cc] = acc[mi][ni][i];
            }
}

// ---------- sin/cos table: tab[0..65535]=cos(t,d), tab[65536..]=sin ----------
__global__ void rope_tab(float* __restrict__ tab) {
    int i = blockIdx.x * 256 + threadIdx.x;   // 65536 = 2048 t x 32 d
    int t = i >> 5, d = i & 31;
    float invf = powf(10000.0f, -(float)d / 32.0f);
    float ang = (float)t * invf;
    tab[i] = cosf(ang);
    tab[i + 65536] = sinf(ang);
}

__device__ __forceinline__ void load64bf(const u16* p, float* v) {
#pragma unroll
    for (int j = 0; j < 8; ++j) {
        uint4 w = *(const uint4*)(p + j * 8);
        unsigned ws[4] = { w.x, w.y, w.z, w.w };
#pragma unroll
        for (int t = 0; t < 4; ++t) {
            union { unsigned u; float f; } a, b;
            a.u = (ws[t] & 0xFFFFu) << 16;
            b.u = ws[t] & 0xFFFF0000u;
            v[j * 8 + 2 * t] = a.f;
            v[j * 8 + 2 * t + 1] = b.f;
        }
    }
}

// ---------- RoPE + pack: C1[4096][3072] bf16 -> qb (pre-scaled), kb, vt ----------
// q is pre-scaled by 0.125*log2(e) so flash softmax runs in exp2 domain.
__global__ void rope_pack(const u16* __restrict__ C1, const float* __restrict__ tab,
                          u16* __restrict__ qb, u16* __restrict__ kb, u16* __restrict__ vt) {
    const float SC = 0.18033688011112042f;   // 0.125 * log2(e)
    int g = blockIdx.x * 256 + threadIdx.x;   // 65536
    int bh = g >> 11;
    int tq = g & 2047;
    int b = bh >> 4, h = bh & 15;
    const u16* base = C1 + (size_t)(b * 2048 + tq) * 3072 + h * 64;

    float cs[32], sn[32];
    const float* tc = tab + tq * 32;
    const float* ts = tab + 65536 + tq * 32;
#pragma unroll
    for (int j = 0; j < 8; ++j) {
        *(float4*)(&cs[j * 4]) = *(const float4*)(tc + j * 4);
        *(float4*)(&sn[j * 4]) = *(const float4*)(ts + j * 4);
    }
    float v[64];
    // ---- q (scaled) ----
    load64bf(base, v);
#pragma unroll
    for (int d = 0; d < 32; ++d) {
        float a = v[d], bb = v[d + 32];
        v[d] = (a * cs[d] - bb * sn[d]) * SC;
        v[d + 32] = (bb * cs[d] + a * sn[d]) * SC;
    }
    {
        u16* dst = qb + ((size_t)bh * 2048 + tq) * 64;
#pragma unroll
        for (int j = 0; j < 8; ++j) {
            uint4 pk;
            pk.x = pack2(v[j * 8 + 0], v[j * 8 + 1]);
            pk.y = pack2(v[j * 8 + 2], v[j * 8 + 3]);
            pk.z = pack2(v[j * 8 + 4], v[j * 8 + 5]);
            pk.w = pack2(v[j * 8 + 6], v[j * 8 + 7]);
            *(uint4*)(dst + j * 8) = pk;
        }
    }
    // ---- k ----
    load64bf(base + 1024, v);
#pragma unroll
    for (int d = 0; d < 32; ++d) {
        float a = v[d], bb = v[d + 32];
        v[d] = a * cs[d] - bb * sn[d];
        v[d + 32] = bb * cs[d] + a * sn[d];
    }
    {
        u16* dst = kb + ((size_t)bh * 2048 + tq) * 64;
#pragma unroll
        for (int j = 0; j < 8; ++j) {
            uint4 pk;
            pk.x = pack2(v[j * 8 + 0], v[j * 8 + 1]);
            pk.y = pack2(v[j * 8 + 2], v[j * 8 + 3]);
            pk.z = pack2(v[j * 8 + 4], v[j * 8 + 5]);
            pk.w = pack2(v[j * 8 + 6], v[j * 8 + 7]);
            *(uint4*)(dst + j * 8) = pk;
        }
    }
    // ---- v (transposed store: vt[bh][dh][t]) ----
    load64bf(base + 2048, v);
#pragma unroll
    for (int d = 0; d < 64; ++d)
        vt[((size_t)bh * 64 + d) * 2048 + tq] = f2bf(v[d]);
}

// ---------- causal flash attention v8: 8 waves, tile-per-wave-group ----------
// waves 0-3 -> tile qtB (16 q-rows each), waves 4-7 -> tile qtA.
// smpack math verbatim from R7-proven flash2e (exp2 domain).
__global__ __launch_bounds__(512, 4) void flash8(const u16* __restrict__ qb,
                                                 const u16* __restrict__ kb,
                                                 const u16* __restrict__ vt,
                                                 u16* __restrict__ ao) {
    __shared__ u16 lK[2][64 * 64];   // [kv][d], XOR-swizzled 16B slots
    __shared__ u16 lV[2][64 * 64];   // [d][kv], XOR-swizzled 16B slots
    const int bh = blockIdx.y;
    const int b = bh >> 4, h = bh & 15;
    const int qtA = blockIdx.x;        // 0..15
    const int qtB = 31 - blockIdx.x;   // 16..31
    const int tid = threadIdx.x;
    const int wave = tid >> 6, lane = tid & 63;
    const int l15 = lane & 15, l4 = lane >> 4;
    const int wsub = wave & 3;
    const int myQt = (wave < 4) ? qtB : qtA;
    const u16* qptr = qb + (size_t)bh * 2048 * 64;
    const u16* kptr = kb + (size_t)bh * 2048 * 64;
    const u16* vptr = vt + (size_t)bh * 64 * 2048;

    // Q fragments (B-operand: col=l15=q, k=l4*8+j=d)
    const int qrow = myQt * 64 + wsub * 16 + l15;
    bf16x8 q0 = *(const bf16x8*)(qptr + (size_t)qrow * 64 + l4 * 8);
    bf16x8 q1 = *(const bf16x8*)(qptr + (size_t)qrow * 64 + 32 + l4 * 8);

    f32x4 O[4] = {};
    float mrun = -INFINITY, lrun = 0.f;

    int idxO[4], idxEx[4];
#pragma unroll
    for (int i = 0; i < 4; ++i) idxO[i] = (lane & 48) | (l4 * 4 + i);
#pragma unroll
    for (int r = 0; r < 4; ++r) idxEx[r] = (((2 * l4 + (r >> 1)) & 3) << 4) | l15;

    // staging: each thread owns one 16B chunk of K and one of V (512 chunks each)
    const int r_st = tid >> 3, s_st = tid & 7;
    const int sd_st = (s_st ^ (r_st & 7)) * 8;   // inverse-swizzled source slot
    auto stage = [&](int buf, int kv0) {
        gload_lds16(kptr + (size_t)(kv0 + r_st) * 64 + sd_st, &lK[buf][wave * 512]);
        gload_lds16(vptr + (size_t)r_st * 2048 + kv0 + sd_st, &lV[buf][wave * 512]);
    };
    auto ldK = [&](int buf, int row, int slot) -> bf16x8 {
        return *(const bf16x8*)(&lK[buf][row * 64 + ((slot ^ (row & 7)) << 3)]);
    };
    auto ldV = [&](int buf, int row, int slot) -> bf16x8 {
        return *(const bf16x8*)(&lV[buf][row * 64 + ((slot ^ (row & 7)) << 3)]);
    };

    // softmax + pack-to-A-frag (VERBATIM from R7 flash2e; P^T in regs: q=l15, kv=c*16+l4*4+i)
    auto smpack = [&](f32x4 S[4], float& mr, float& lr, f32x4 Ov[4],
                      bf16x8 af[2], bool diag, int kv0, int qr) {
        float p[4][4];
#pragma unroll
        for (int c = 0; c < 4; ++c)
#pragma unroll
            for (int i = 0; i < 4; ++i) {
                float s = S[c][i];
                if (diag && (kv0 + c * 16 + l4 * 4 + i > qr)) s = -INFINITY;
                p[c][i] = s;
            }
        float m = p[0][0];
#pragma unroll
        for (int c = 0; c < 4; ++c)
#pragma unroll
            for (int i = 0; i < 4; ++i) m = fmaxf(m, p[c][i]);
        m = fmaxf(m, __shfl_xor(m, 16));
        m = fmaxf(m, __shfl_xor(m, 32));
        float mnew = fmaxf(mr, m);
        float corr = __builtin_amdgcn_exp2f(mr - mnew);
        float rs = 0.f;
#pragma unroll
        for (int c = 0; c < 4; ++c)
#pragma unroll
            for (int i = 0; i < 4; ++i) { p[c][i] = __builtin_amdgcn_exp2f(p[c][i] - mnew); rs += p[c][i]; }
        rs += __shfl_xor(rs, 16);
        rs += __shfl_xor(rs, 32);
        lr = lr * corr + rs;
        mr = mnew;
#pragma unroll
        for (int i = 0; i < 4; ++i) {
            float cf = __shfl(corr, idxO[i]);
#pragma unroll
            for (int c2 = 0; c2 < 4; ++c2) Ov[c2][i] *= cf;
        }
        unsigned w[4][2];
#pragma unroll
        for (int c = 0; c < 4; ++c) {
            asm("v_cvt_pk_bf16_f32 %0, %1, %2" : "=v"(w[c][0]) : "v"(p[c][0]), "v"(p[c][1]));
            asm("v_cvt_pk_bf16_f32 %0, %1, %2" : "=v"(w[c][1]) : "v"(p[c][2]), "v"(p[c][3]));
        }
#pragma unroll
        for (int ks = 0; ks < 2; ++ks) {
            unsigned a0, a1, a2, a3;
            {
                unsigned lo = __shfl((int)w[2 * ks][0], idxEx[0]);
                unsigned hi = __shfl((int)w[2 * ks + 1][0], idxEx[0]);
                a0 = (l4 < 2) ? lo : hi;
            }
            {
                unsigned lo = __shfl((int)w[2 * ks][1], idxEx[1]);
                unsigned hi = __shfl((int)w[2 * ks + 1][1], idxEx[1]);
                a1 = (l4 < 2) ? lo : hi;
            }
            {
                unsigned lo = __shfl((int)w[2 * ks][0], idxEx[2]);
                unsigned hi = __shfl((int)w[2 * ks + 1][0], idxEx[2]);
                a2 = (l4 < 2) ? lo : hi;
            }
            {
                unsigned lo = __shfl((int)w[2 * ks][1], idxEx[3]);
                unsigned hi = __shfl((int)w[2 * ks + 1][1], idxEx[3]);
                a3 = (l4 < 2) ? lo : hi;
            }
            union { unsigned u[4]; bf16x8 v; } cvt;
            cvt.u[0] = a0; cvt.u[1] = a1; cvt.u[2] = a2; cvt.u[3] = a3;
            af[ks] = cvt.v;
        }
    };

    stage(0, 0);
    for (int kvb = 0; kvb <= qtB; ++kvb) {
        const int cur = kvb & 1;
        const int kv0 = kvb * 64;
        if (kvb < qtB) {
            stage(cur ^ 1, kv0 + 64);
            asm volatile("s_waitcnt vmcnt(2)" ::: "memory");
        } else {
            asm volatile("s_waitcnt vmcnt(0)" ::: "memory");
        }
        __builtin_amdgcn_s_barrier();
        __builtin_amdgcn_sched_barrier(0);

        if (kvb <= myQt) {
            // QK^T swapped: S'[kv][q]
            f32x4 S[4] = {};
#pragma unroll
            for (int c = 0; c < 4; ++c) {
                bf16x8 kf0 = ldK(cur, c * 16 + l15, l4);
                bf16x8 kf1 = ldK(cur, c * 16 + l15, 4 + l4);
                S[c] = mfma16(kf0, q0, S[c]);
                S[c] = mfma16(kf1, q1, S[c]);
            }
            bf16x8 af[2];
            smpack(S, mrun, lrun, O, af, kvb == myQt, kv0, qrow);
#pragma unroll
            for (int ks = 0; ks < 2; ++ks)
#pragma unroll
                for (int c2 = 0; c2 < 4; ++c2) {
                    bf16x8 vf = ldV(cur, c2 * 16 + l15, ks * 4 + l4);
                    O[c2] = mfma16(af[ks], vf, O[c2]);
                }
        }
        __builtin_amdgcn_s_barrier();   // protect buffer overwrite by next stage
    }

    // epilogue: O rows are q'=l4*4+i, cols d=c2*16+l15
#pragma unroll
    for (int i = 0; i < 4; ++i) {
        float lv = __shfl(lrun, idxO[i]);
        float rcp = 1.f / lv;
        int qg = myQt * 64 + wsub * 16 + l4 * 4 + i;
#pragma unroll
        for (int c2 = 0; c2 < 4; ++c2)
            ao[(size_t)(b * 2048 + qg) * 1024 + h * 64 + c2 * 16 + l15] = f2bf(O[c2][i] * rcp);
    }
}

// ---------- launch ----------
extern "C" void kernel_launch(void* const* d_in, const int* in_sizes, int n_in,
                              void* d_out, int out_size, void* d_ws, size_t ws_size,
                              hipStream_t stream) {
    const float* x    = (const float*)d_in[0];   // (2,2048,1024)
    const float* Wqkv = (const float*)d_in[1];   // (1024,3072)
    const float* Wout = (const float*)d_in[2];   // (1024,1024)
    float* out = (float*)d_out;                  // (2,2048,1024)
    char* ws = (char*)d_ws;

    u16*   xb  = (u16*)(ws + 0);            // 8 MB  (4096x1024 bf16)
    u16*   Wtq = (u16*)(ws + 8388608);      // 6 MB  (3072x1024 bf16)
    u16*   Wto = (u16*)(ws + 14680064);     // 2 MB  (1024x1024 bf16)
    u16*   C1b = (u16*)(ws + 16777216);     // 24 MB (4096x3072 bf16)
    u16*   qb  = (u16*)(ws + 67108864);     // 8 MB  (B,H,T,Dh bf16, pre-scaled)
    u16*   kb  = (u16*)(ws + 75497472);     // 8 MB
    u16*   vt  = (u16*)(ws + 83886080);     // 8 MB  (B,H,Dh,T bf16)
    float* tab = (float*)(ws + 92274688);   // 512 KB sin/cos table
    u16*   ao  = (u16*)(ws + 0);            // reuse xb region (GEMM1 done by then)

    cvt_bf16<<<dim3(4096), dim3(256), 0, stream>>>(x, xb);
    transpose_cvt<<<dim3(96, 32), dim3(256), 0, stream>>>(Wqkv, Wtq, 1024, 3072);
    transpose_cvt<<<dim3(32, 32), dim3(256), 0, stream>>>(Wout, Wto, 1024, 1024);
    rope_tab<<<dim3(256), dim3(256), 0, stream>>>(tab);
    gemm_bt<true><<<dim3(24, 32), dim3(256), 0, stream>>>(xb, Wtq, (void*)C1b, 4096, 3072, 1024);
    rope_pack<<<dim3(256), dim3(256), 0, stream>>>(C1b, tab, qb, kb, vt);
    flash8<<<dim3(16, 32), dim3(512), 0, stream>>>(qb, kb, vt, ao);
    gemm_bt<false><<<dim3(8, 32), dim3(256), 0, stream>>>(ao, Wto, (void*)out, 4096, 1024, 1024);
}

// Round 9
// 138.422 us; speedup vs baseline: 2.0127x; 1.1064x over previous
//
#include <hip/hip_runtime.h>
#include <math.h>

typedef unsigned short u16;
typedef short bf16x8 __attribute__((ext_vector_type(8)));
typedef float f32x4 __attribute__((ext_vector_type(4)));

// ---------- helpers ----------
__device__ __forceinline__ u16 f2bf(float f) {
    union { float f; unsigned u; } x; x.f = f;
    unsigned u = x.u;
    unsigned r = (u + 0x7fffu + ((u >> 16) & 1u)) >> 16;   // RNE, no NaN in data
    return (u16)r;
}
__device__ __forceinline__ unsigned pack2(float a, float b) {
    return (unsigned)f2bf(a) | ((unsigned)f2bf(b) << 16);
}
__device__ __forceinline__ f32x4 mfma16(bf16x8 a, bf16x8 b, f32x4 c) {
    return __builtin_amdgcn_mfma_f32_16x16x32_bf16(a, b, c, 0, 0, 0);
}
__device__ __forceinline__ void gload_lds16(const void* g, void* l) {
    __builtin_amdgcn_global_load_lds((const __attribute__((address_space(1))) void*)g,
                                     (__attribute__((address_space(3))) void*)l,
                                     16, 0, 0);
}

// ---------- fp32 -> bf16 cast (vectorized) ----------
__global__ void cvt_bf16(const float* __restrict__ X, u16* __restrict__ Y) {
    int i = (blockIdx.x * 256 + threadIdx.x) * 4;
    float4 v = *(const float4*)(X + i);
    uint2 o;
    o.x = pack2(v.x, v.y);
    o.y = pack2(v.z, v.w);
    *(uint2*)(Y + i) = o;
}

// ---------- W[R][C] fp32 -> Wt[C][R] bf16 (LDS-tiled transpose) ----------
__global__ void transpose_cvt(const float* __restrict__ W, u16* __restrict__ Wt,
                              int R, int C) {
    __shared__ u16 tile[32][33];
    int tx = threadIdx.x & 31, ty = threadIdx.x >> 5;  // 32 x 8
    int bx = blockIdx.x * 32;
    int by = blockIdx.y * 32;
#pragma unroll
    for (int r = ty; r < 32; r += 8)
        tile[r][tx] = f2bf(W[(size_t)(by + r) * C + bx + tx]);
    __syncthreads();
#pragma unroll
    for (int r = ty; r < 32; r += 8)
        Wt[(size_t)(bx + r) * R + by + tx] = tile[tx][r];
}

// ---------- GEMM: C[M][N] = A[M][K] * Bt[N][K]^T, 128x128, BK=64, XOR-swizzled LDS ----------
template <bool BF16OUT>
__global__ __launch_bounds__(256) void gemm_bt(const u16* __restrict__ A,
                                               const u16* __restrict__ Bt,
                                               void* __restrict__ Cv,
                                               int M, int N, int K) {
    __shared__ u16 lA[128 * 64];
    __shared__ u16 lB[128 * 64];
    const int tid = threadIdx.x;
    const int wave = tid >> 6, lane = tid & 63;
    const int l15 = lane & 15, l4 = lane >> 4;
    const int m0 = blockIdx.y * 128, n0 = blockIdx.x * 128;
    const int wm = (wave >> 1) * 64, wn = (wave & 1) * 64;
    f32x4 acc[4][4] = {};
    for (int k0 = 0; k0 < K; k0 += 64) {
#pragma unroll
        for (int it = 0; it < 4; ++it) {
            int c = it * 256 + wave * 64 + lane;
            int r = c >> 3, s = c & 7;
            int sd = ((s ^ (r & 7)) << 3);   // inverse-swizzled source slot
            gload_lds16(A + (size_t)(m0 + r) * K + k0 + sd,
                        &lA[(size_t)(it * 256 + wave * 64) * 8]);
            gload_lds16(Bt + (size_t)(n0 + r) * K + k0 + sd,
                        &lB[(size_t)(it * 256 + wave * 64) * 8]);
        }
        __syncthreads();
#pragma unroll
        for (int kk = 0; kk < 2; ++kk) {
            bf16x8 af[4], bf[4];
#pragma unroll
            for (int mi = 0; mi < 4; ++mi) {
                int row = wm + mi * 16 + l15;
                af[mi] = *(const bf16x8*)(&lA[row * 64 + (((kk * 4 + l4) ^ (row & 7)) << 3)]);
            }
#pragma unroll
            for (int ni = 0; ni < 4; ++ni) {
                int row = wn + ni * 16 + l15;
                bf[ni] = *(const bf16x8*)(&lB[row * 64 + (((kk * 4 + l4) ^ (row & 7)) << 3)]);
            }
#pragma unroll
            for (int mi = 0; mi < 4; ++mi)
#pragma unroll
                for (int ni = 0; ni < 4; ++ni)
                    acc[mi][ni] = mfma16(af[mi], bf[ni], acc[mi][ni]);
        }
        __syncthreads();
    }
#pragma unroll
    for (int mi = 0; mi < 4; ++mi)
#pragma unroll
        for (int ni = 0; ni < 4; ++ni)
#pragma unroll
            for (int i = 0; i < 4; ++i) {
                int r = m0 + wm + mi * 16 + l4 * 4 + i;
                int cc = n0 + wn + ni * 16 + l15;
                if constexpr (BF16OUT)
                    ((u16*)Cv)[(size_t)r * N + cc] = f2bf(acc[mi][ni][i]);
                else
                    ((float*)Cv)[(size_t)r * N + cc] = acc[mi][ni][i];
            }
}

// ---------- GEMM 128x64 tile (for small-N final proj): grid (N/64, M/128) ----------
__global__ __launch_bounds__(256) void gemm_bt_n64(const u16* __restrict__ A,
                                                   const u16* __restrict__ Bt,
                                                   float* __restrict__ C,
                                                   int M, int N, int K) {
    __shared__ u16 lA[128 * 64];
    __shared__ u16 lB[64 * 64];
    const int tid = threadIdx.x;
    const int wave = tid >> 6, lane = tid & 63;
    const int l15 = lane & 15, l4 = lane >> 4;
    const int m0 = blockIdx.y * 128, n0 = blockIdx.x * 64;
    const int wm = (wave >> 1) * 64, wn = (wave & 1) * 32;
    f32x4 acc[4][2] = {};
    for (int k0 = 0; k0 < K; k0 += 64) {
#pragma unroll
        for (int it = 0; it < 4; ++it) {
            int c = it * 256 + wave * 64 + lane;
            int r = c >> 3, s = c & 7;
            int sd = ((s ^ (r & 7)) << 3);
            gload_lds16(A + (size_t)(m0 + r) * K + k0 + sd,
                        &lA[(size_t)(it * 256 + wave * 64) * 8]);
        }
#pragma unroll
        for (int it = 0; it < 2; ++it) {
            int c = it * 256 + wave * 64 + lane;
            int r = c >> 3, s = c & 7;
            int sd = ((s ^ (r & 7)) << 3);
            gload_lds16(Bt + (size_t)(n0 + r) * K + k0 + sd,
                        &lB[(size_t)(it * 256 + wave * 64) * 8]);
        }
        __syncthreads();
#pragma unroll
        for (int kk = 0; kk < 2; ++kk) {
            bf16x8 af[4], bf[2];
#pragma unroll
            for (int mi = 0; mi < 4; ++mi) {
                int row = wm + mi * 16 + l15;
                af[mi] = *(const bf16x8*)(&lA[row * 64 + (((kk * 4 + l4) ^ (row & 7)) << 3)]);
            }
#pragma unroll
            for (int ni = 0; ni < 2; ++ni) {
                int row = wn + ni * 16 + l15;
                bf[ni] = *(const bf16x8*)(&lB[row * 64 + (((kk * 4 + l4) ^ (row & 7)) << 3)]);
            }
#pragma unroll
            for (int mi = 0; mi < 4; ++mi)
#pragma unroll
                for (int ni = 0; ni < 2; ++ni)
                    acc[mi][ni] = mfma16(af[mi], bf[ni], acc[mi][ni]);
        }
        __syncthreads();
    }
#pragma unroll
    for (int mi = 0; mi < 4; ++mi)
#pragma unroll
        for (int ni = 0; ni < 2; ++ni)
#pragma unroll
            for (int i = 0; i < 4; ++i) {
                int r = m0 + wm + mi * 16 + l4 * 4 + i;
                int cc = n0 + wn + ni * 16 + l15;
                C[(size_t)r * N + cc] = acc[mi][ni][i];
            }
}

// ---------- sin/cos table: tab[0..65535]=cos(t,d), tab[65536..]=sin ----------
__global__ void rope_tab(float* __restrict__ tab) {
    int i = blockIdx.x * 256 + threadIdx.x;   // 65536 = 2048 t x 32 d
    int t = i >> 5, d = i & 31;
    float invf = powf(10000.0f, -(float)d / 32.0f);
    float ang = (float)t * invf;
    tab[i] = cosf(ang);
    tab[i + 65536] = sinf(ang);
}

__device__ __forceinline__ void load64bf(const u16* p, float* v) {
#pragma unroll
    for (int j = 0; j < 8; ++j) {
        uint4 w = *(const uint4*)(p + j * 8);
        unsigned ws[4] = { w.x, w.y, w.z, w.w };
#pragma unroll
        for (int t = 0; t < 4; ++t) {
            union { unsigned u; float f; } a, b;
            a.u = (ws[t] & 0xFFFFu) << 16;
            b.u = ws[t] & 0xFFFF0000u;
            v[j * 8 + 2 * t] = a.f;
            v[j * 8 + 2 * t + 1] = b.f;
        }
    }
}

// ---------- RoPE + pack: C1[4096][3072] bf16 -> qb (pre-scaled), kb, vt ----------
// q is pre-scaled by 0.125*log2(e) so flash softmax runs in exp2 domain.
__global__ void rope_pack(const u16* __restrict__ C1, const float* __restrict__ tab,
                          u16* __restrict__ qb, u16* __restrict__ kb, u16* __restrict__ vt) {
    const float SC = 0.18033688011112042f;   // 0.125 * log2(e)
    int g = blockIdx.x * 256 + threadIdx.x;   // 65536
    int bh = g >> 11;
    int tq = g & 2047;
    int b = bh >> 4, h = bh & 15;
    const u16* base = C1 + (size_t)(b * 2048 + tq) * 3072 + h * 64;

    float cs[32], sn[32];
    const float* tc = tab + tq * 32;
    const float* ts = tab + 65536 + tq * 32;
#pragma unroll
    for (int j = 0; j < 8; ++j) {
        *(float4*)(&cs[j * 4]) = *(const float4*)(tc + j * 4);
        *(float4*)(&sn[j * 4]) = *(const float4*)(ts + j * 4);
    }
    float v[64];
    // ---- q (scaled) ----
    load64bf(base, v);
#pragma unroll
    for (int d = 0; d < 32; ++d) {
        float a = v[d], bb = v[d + 32];
        v[d] = (a * cs[d] - bb * sn[d]) * SC;
        v[d + 32] = (bb * cs[d] + a * sn[d]) * SC;
    }
    {
        u16* dst = qb + ((size_t)bh * 2048 + tq) * 64;
#pragma unroll
        for (int j = 0; j < 8; ++j) {
            uint4 pk;
            pk.x = pack2(v[j * 8 + 0], v[j * 8 + 1]);
            pk.y = pack2(v[j * 8 + 2], v[j * 8 + 3]);
            pk.z = pack2(v[j * 8 + 4], v[j * 8 + 5]);
            pk.w = pack2(v[j * 8 + 6], v[j * 8 + 7]);
            *(uint4*)(dst + j * 8) = pk;
        }
    }
    // ---- k ----
    load64bf(base + 1024, v);
#pragma unroll
    for (int d = 0; d < 32; ++d) {
        float a = v[d], bb = v[d + 32];
        v[d] = a * cs[d] - bb * sn[d];
        v[d + 32] = bb * cs[d] + a * sn[d];
    }
    {
        u16* dst = kb + ((size_t)bh * 2048 + tq) * 64;
#pragma unroll
        for (int j = 0; j < 8; ++j) {
            uint4 pk;
            pk.x = pack2(v[j * 8 + 0], v[j * 8 + 1]);
            pk.y = pack2(v[j * 8 + 2], v[j * 8 + 3]);
            pk.z = pack2(v[j * 8 + 4], v[j * 8 + 5]);
            pk.w = pack2(v[j * 8 + 6], v[j * 8 + 7]);
            *(uint4*)(dst + j * 8) = pk;
        }
    }
    // ---- v (transposed store: vt[bh][dh][t]) ----
    load64bf(base + 2048, v);
#pragma unroll
    for (int d = 0; d < 64; ++d)
        vt[((size_t)bh * 64 + d) * 2048 + tq] = f2bf(v[d]);
}

// ---------- causal flash attention v9: pi-scrambled K rows => ZERO-shuffle P->PV ----------
// K rows read per MFMA m at A-row r: kv = 32(m>>1) + 4(m&1) + 8(r>>2) + (r&3).
// Lane (l4,l15) then holds S at kv = 32(m>>1) + 8*l4 + 4(m&1) + i, which IS the
// PV A-fragment layout (kv = 32ks + 8*l4 + j, j=4(m&1)+i): af built by local cvt_pk.
// K LDS swizzle: f(row) = (row&3)|((row>>1)&4) (pi row set varies bits 0-1,3-4 only).
__global__ __launch_bounds__(512, 4) void flash9(const u16* __restrict__ qb,
                                                 const u16* __restrict__ kb,
                                                 const u16* __restrict__ vt,
                                                 u16* __restrict__ ao) {
    __shared__ u16 lK[2][64 * 64];   // [kv][d], f_K-XOR-swizzled 16B slots
    __shared__ u16 lV[2][64 * 64];   // [d][kv], row&7-XOR-swizzled 16B slots
    const int bh = blockIdx.y;
    const int b = bh >> 4, h = bh & 15;
    const int qtA = blockIdx.x;        // 0..15
    const int qtB = 31 - blockIdx.x;   // 16..31
    const int tid = threadIdx.x;
    const int wave = tid >> 6, lane = tid & 63;
    const int l15 = lane & 15, l4 = lane >> 4;
    const int wsub = wave & 3;
    const int myQt = (wave < 4) ? qtB : qtA;
    const u16* qptr = qb + (size_t)bh * 2048 * 64;
    const u16* kptr = kb + (size_t)bh * 2048 * 64;
    const u16* vptr = vt + (size_t)bh * 64 * 2048;

    // Q fragments (B-operand: col=l15=q, k=l4*8+j=d)
    const int qrow = myQt * 64 + wsub * 16 + l15;
    bf16x8 q0 = *(const bf16x8*)(qptr + (size_t)qrow * 64 + l4 * 8);
    bf16x8 q1 = *(const bf16x8*)(qptr + (size_t)qrow * 64 + 32 + l4 * 8);

    f32x4 O[4] = {};
    float mrun = -INFINITY, lrun = 0.f;

    int idxO[4];
#pragma unroll
    for (int i = 0; i < 4; ++i) idxO[i] = (lane & 48) | (l4 * 4 + i);

    // pi base row for this lane's A-operand reads (QK)
    const int r0q = ((l15 >> 2) << 3) | (l15 & 3);

    // staging: each thread owns one 16B chunk of K and one of V (512 chunks each)
    const int r_st = tid >> 3, s_st = tid & 7;
    const int fK_st = (r_st & 3) | ((r_st >> 1) & 4);
    const int sdK_st = (s_st ^ fK_st) * 8;       // inverse-swizzled K source slot
    const int sdV_st = (s_st ^ (r_st & 7)) * 8;  // inverse-swizzled V source slot
    auto stage = [&](int buf, int kv0) {
        gload_lds16(kptr + (size_t)(kv0 + r_st) * 64 + sdK_st, &lK[buf][wave * 512]);
        gload_lds16(vptr + (size_t)r_st * 2048 + kv0 + sdV_st, &lV[buf][wave * 512]);
    };
    auto ldK = [&](int buf, int row, int slot) -> bf16x8 {
        int f = (row & 3) | ((row >> 1) & 4);
        return *(const bf16x8*)(&lK[buf][row * 64 + ((slot ^ f) << 3)]);
    };
    auto ldV = [&](int buf, int row, int slot) -> bf16x8 {
        return *(const bf16x8*)(&lV[buf][row * 64 + ((slot ^ (row & 7)) << 3)]);
    };

    // softmax + pack-to-A-frag; p[m][i] at kv = kv0 + 32(m>>1) + 8*l4 + 4(m&1) + i
    auto smpack = [&](f32x4 S[4], float& mr, float& lr, f32x4 Ov[4],
                      bf16x8 af[2], bool diag, int kv0, int qr) {
        float p[4][4];
#pragma unroll
        for (int m = 0; m < 4; ++m)
#pragma unroll
            for (int i = 0; i < 4; ++i) {
                float s = S[m][i];
                if (diag && (kv0 + ((m >> 1) << 5) + (l4 << 3) + ((m & 1) << 2) + i > qr))
                    s = -INFINITY;
                p[m][i] = s;
            }
        float m = p[0][0];
#pragma unroll
        for (int c = 0; c < 4; ++c)
#pragma unroll
            for (int i = 0; i < 4; ++i) m = fmaxf(m, p[c][i]);
        m = fmaxf(m, __shfl_xor(m, 16));
        m = fmaxf(m, __shfl_xor(m, 32));
        float mnew = fmaxf(mr, m);
        float corr = __builtin_amdgcn_exp2f(mr - mnew);
        float rs = 0.f;
#pragma unroll
        for (int c = 0; c < 4; ++c)
#pragma unroll
            for (int i = 0; i < 4; ++i) { p[c][i] = __builtin_amdgcn_exp2f(p[c][i] - mnew); rs += p[c][i]; }
        rs += __shfl_xor(rs, 16);
        rs += __shfl_xor(rs, 32);
        lr = lr * corr + rs;
        mr = mnew;
#pragma unroll
        for (int i = 0; i < 4; ++i) {
            float cf = __shfl(corr, idxO[i]);
#pragma unroll
            for (int c2 = 0; c2 < 4; ++c2) Ov[c2][i] *= cf;
        }
        // direct pack: af[ks] = {pk(p[2ks][0],p[2ks][1]), pk(p[2ks][2],p[2ks][3]),
        //                        pk(p[2ks+1][0],p[2ks+1][1]), pk(p[2ks+1][2],p[2ks+1][3])}
        unsigned w[4][2];
#pragma unroll
        for (int c = 0; c < 4; ++c) {
            asm("v_cvt_pk_bf16_f32 %0, %1, %2" : "=v"(w[c][0]) : "v"(p[c][0]), "v"(p[c][1]));
            asm("v_cvt_pk_bf16_f32 %0, %1, %2" : "=v"(w[c][1]) : "v"(p[c][2]), "v"(p[c][3]));
        }
#pragma unroll
        for (int ks = 0; ks < 2; ++ks) {
            union { unsigned u[4]; bf16x8 v; } cvt;
            cvt.u[0] = w[2 * ks][0];
            cvt.u[1] = w[2 * ks][1];
            cvt.u[2] = w[2 * ks + 1][0];
            cvt.u[3] = w[2 * ks + 1][1];
            af[ks] = cvt.v;
        }
    };

    stage(0, 0);
    for (int kvb = 0; kvb <= qtB; ++kvb) {
        const int cur = kvb & 1;
        const int kv0 = kvb * 64;
        if (kvb < qtB) {
            stage(cur ^ 1, kv0 + 64);
            asm volatile("s_waitcnt vmcnt(2)" ::: "memory");
        } else {
            asm volatile("s_waitcnt vmcnt(0)" ::: "memory");
        }
        __builtin_amdgcn_s_barrier();
        __builtin_amdgcn_sched_barrier(0);

        if (kvb <= myQt) {
            // QK^T swapped with pi-scrambled A-rows: S[m] rows = kv subset of MFMA m
            f32x4 S[4] = {};
#pragma unroll
            for (int mm = 0; mm < 4; ++mm) {
                int row = r0q + ((mm >> 1) << 5) + ((mm & 1) << 2);
                bf16x8 kf0 = ldK(cur, row, l4);
                bf16x8 kf1 = ldK(cur, row, 4 + l4);
                S[mm] = mfma16(kf0, q0, S[mm]);
                S[mm] = mfma16(kf1, q1, S[mm]);
            }
            bf16x8 af[2];
            smpack(S, mrun, lrun, O, af, kvb == myQt, kv0, qrow);
#pragma unroll
            for (int ks = 0; ks < 2; ++ks)
#pragma unroll
                for (int c2 = 0; c2 < 4; ++c2) {
                    bf16x8 vf = ldV(cur, c2 * 16 + l15, ks * 4 + l4);
                    O[c2] = mfma16(af[ks], vf, O[c2]);
                }
        }
        __builtin_amdgcn_s_barrier();   // protect buffer overwrite by next stage
    }

    // epilogue: O rows are q'=l4*4+i, cols d=c2*16+l15
#pragma unroll
    for (int i = 0; i < 4; ++i) {
        float lv = __shfl(lrun, idxO[i]);
        float rcp = 1.f / lv;
        int qg = myQt * 64 + wsub * 16 + l4 * 4 + i;
#pragma unroll
        for (int c2 = 0; c2 < 4; ++c2)
            ao[(size_t)(b * 2048 + qg) * 1024 + h * 64 + c2 * 16 + l15] = f2bf(O[c2][i] * rcp);
    }
}

// ---------- launch ----------
extern "C" void kernel_launch(void* const* d_in, const int* in_sizes, int n_in,
                              void* d_out, int out_size, void* d_ws, size_t ws_size,
                              hipStream_t stream) {
    const float* x    = (const float*)d_in[0];   // (2,2048,1024)
    const float* Wqkv = (const float*)d_in[1];   // (1024,3072)
    const float* Wout = (const float*)d_in[2];   // (1024,1024)
    float* out = (float*)d_out;                  // (2,2048,1024)
    char* ws = (char*)d_ws;

    u16*   xb  = (u16*)(ws + 0);            // 8 MB  (4096x1024 bf16)
    u16*   Wtq = (u16*)(ws + 8388608);      // 6 MB  (3072x1024 bf16)
    u16*   Wto = (u16*)(ws + 14680064);     // 2 MB  (1024x1024 bf16)
    u16*   C1b = (u16*)(ws + 16777216);     // 24 MB (4096x3072 bf16)
    u16*   qb  = (u16*)(ws + 67108864);     // 8 MB  (B,H,T,Dh bf16, pre-scaled)
    u16*   kb  = (u16*)(ws + 75497472);     // 8 MB
    u16*   vt  = (u16*)(ws + 83886080);     // 8 MB  (B,H,Dh,T bf16)
    float* tab = (float*)(ws + 92274688);   // 512 KB sin/cos table
    u16*   ao  = (u16*)(ws + 0);            // reuse xb region (GEMM1 done by then)

    cvt_bf16<<<dim3(4096), dim3(256), 0, stream>>>(x, xb);
    transpose_cvt<<<dim3(96, 32), dim3(256), 0, stream>>>(Wqkv, Wtq, 1024, 3072);
    transpose_cvt<<<dim3(32, 32), dim3(256), 0, stream>>>(Wout, Wto, 1024, 1024);
    rope_tab<<<dim3(256), dim3(256), 0, stream>>>(tab);
    gemm_bt<true><<<dim3(24, 32), dim3(256), 0, stream>>>(xb, Wtq, (void*)C1b, 4096, 3072, 1024);
    rope_pack<<<dim3(256), dim3(256), 0, stream>>>(C1b, tab, qb, kb, vt);
    flash9<<<dim3(16, 32), dim3(512), 0, stream>>>(qb, kb, vt, ao);
    gemm_bt_n64<<<dim3(16, 32), dim3(256), 0, stream>>>(ao, Wto, out, 4096, 1024, 1024);
}

// Round 10
// 133.109 us; speedup vs baseline: 2.0930x; 1.0399x over previous
//
#include <hip/hip_runtime.h>
#include <math.h>

typedef unsigned short u16;
typedef short bf16x8 __attribute__((ext_vector_type(8)));
typedef float f32x4 __attribute__((ext_vector_type(4)));

// ---------- helpers ----------
__device__ __forceinline__ u16 f2bf(float f) {
    union { float f; unsigned u; } x; x.f = f;
    unsigned u = x.u;
    unsigned r = (u + 0x7fffu + ((u >> 16) & 1u)) >> 16;   // RNE, no NaN in data
    return (u16)r;
}
__device__ __forceinline__ unsigned pack2(float a, float b) {
    return (unsigned)f2bf(a) | ((unsigned)f2bf(b) << 16);
}
__device__ __forceinline__ f32x4 mfma16(bf16x8 a, bf16x8 b, f32x4 c) {
    return __builtin_amdgcn_mfma_f32_16x16x32_bf16(a, b, c, 0, 0, 0);
}
__device__ __forceinline__ void gload_lds16(const void* g, void* l) {
    __builtin_amdgcn_global_load_lds((const __attribute__((address_space(1))) void*)g,
                                     (__attribute__((address_space(3))) void*)l,
                                     16, 0, 0);
}

// ---------- fp32 -> bf16 cast (vectorized) ----------
__global__ void cvt_bf16(const float* __restrict__ X, u16* __restrict__ Y) {
    int i = (blockIdx.x * 256 + threadIdx.x) * 4;
    float4 v = *(const float4*)(X + i);
    uint2 o;
    o.x = pack2(v.x, v.y);
    o.y = pack2(v.z, v.w);
    *(uint2*)(Y + i) = o;
}

// ---------- W[R][C] fp32 -> Wt[C][R] bf16 (LDS-tiled transpose) ----------
__global__ void transpose_cvt(const float* __restrict__ W, u16* __restrict__ Wt,
                              int R, int C) {
    __shared__ u16 tile[32][33];
    int tx = threadIdx.x & 31, ty = threadIdx.x >> 5;  // 32 x 8
    int bx = blockIdx.x * 32;
    int by = blockIdx.y * 32;
#pragma unroll
    for (int r = ty; r < 32; r += 8)
        tile[r][tx] = f2bf(W[(size_t)(by + r) * C + bx + tx]);
    __syncthreads();
#pragma unroll
    for (int r = ty; r < 32; r += 8)
        Wt[(size_t)(bx + r) * R + by + tx] = tile[tx][r];
}

// ---------- GEMM: C[M][N] = A[M][K] * Bt[N][K]^T, 128x128, BK=64, XOR-swizzled LDS ----------
// T1: XCD-aware block swizzle (nwg must be %8==0; 768 and 512 both are)
template <bool BF16OUT>
__global__ __launch_bounds__(256) void gemm_bt(const u16* __restrict__ A,
                                               const u16* __restrict__ Bt,
                                               void* __restrict__ Cv,
                                               int M, int N, int K) {
    __shared__ u16 lA[128 * 64];
    __shared__ u16 lB[128 * 64];
    const int tid = threadIdx.x;
    const int wave = tid >> 6, lane = tid & 63;
    const int l15 = lane & 15, l4 = lane >> 4;
    const int nwg = gridDim.x * gridDim.y;
    const int orig = blockIdx.y * gridDim.x + blockIdx.x;
    const int swz = (orig & 7) * (nwg >> 3) + (orig >> 3);
    const int m0 = (swz / gridDim.x) * 128, n0 = (swz % gridDim.x) * 128;
    const int wm = (wave >> 1) * 64, wn = (wave & 1) * 64;
    f32x4 acc[4][4] = {};
    for (int k0 = 0; k0 < K; k0 += 64) {
#pragma unroll
        for (int it = 0; it < 4; ++it) {
            int c = it * 256 + wave * 64 + lane;
            int r = c >> 3, s = c & 7;
            int sd = ((s ^ (r & 7)) << 3);   // inverse-swizzled source slot
            gload_lds16(A + (size_t)(m0 + r) * K + k0 + sd,
                        &lA[(size_t)(it * 256 + wave * 64) * 8]);
            gload_lds16(Bt + (size_t)(n0 + r) * K + k0 + sd,
                        &lB[(size_t)(it * 256 + wave * 64) * 8]);
        }
        __syncthreads();
#pragma unroll
        for (int kk = 0; kk < 2; ++kk) {
            bf16x8 af[4], bf[4];
#pragma unroll
            for (int mi = 0; mi < 4; ++mi) {
                int row = wm + mi * 16 + l15;
                af[mi] = *(const bf16x8*)(&lA[row * 64 + (((kk * 4 + l4) ^ (row & 7)) << 3)]);
            }
#pragma unroll
            for (int ni = 0; ni < 4; ++ni) {
                int row = wn + ni * 16 + l15;
                bf[ni] = *(const bf16x8*)(&lB[row * 64 + (((kk * 4 + l4) ^ (row & 7)) << 3)]);
            }
#pragma unroll
            for (int mi = 0; mi < 4; ++mi)
#pragma unroll
                for (int ni = 0; ni < 4; ++ni)
                    acc[mi][ni] = mfma16(af[mi], bf[ni], acc[mi][ni]);
        }
        __syncthreads();
    }
#pragma unroll
    for (int mi = 0; mi < 4; ++mi)
#pragma unroll
        for (int ni = 0; ni < 4; ++ni)
#pragma unroll
            for (int i = 0; i < 4; ++i) {
                int r = m0 + wm + mi * 16 + l4 * 4 + i;
                int cc = n0 + wn + ni * 16 + l15;
                if constexpr (BF16OUT)
                    ((u16*)Cv)[(size_t)r * N + cc] = f2bf(acc[mi][ni][i]);
                else
                    ((float*)Cv)[(size_t)r * N + cc] = acc[mi][ni][i];
            }
}

// ---------- GEMM 128x64 tile (final proj): grid (N/64, M/128), T1 swizzle ----------
__global__ __launch_bounds__(256) void gemm_bt_n64(const u16* __restrict__ A,
                                                   const u16* __restrict__ Bt,
                                                   float* __restrict__ C,
                                                   int M, int N, int K) {
    __shared__ u16 lA[128 * 64];
    __shared__ u16 lB[64 * 64];
    const int tid = threadIdx.x;
    const int wave = tid >> 6, lane = tid & 63;
    const int l15 = lane & 15, l4 = lane >> 4;
    const int nwg = gridDim.x * gridDim.y;
    const int orig = blockIdx.y * gridDim.x + blockIdx.x;
    const int swz = (orig & 7) * (nwg >> 3) + (orig >> 3);
    const int m0 = (swz / gridDim.x) * 128, n0 = (swz % gridDim.x) * 64;
    const int wm = (wave >> 1) * 64, wn = (wave & 1) * 32;
    f32x4 acc[4][2] = {};
    for (int k0 = 0; k0 < K; k0 += 64) {
#pragma unroll
        for (int it = 0; it < 4; ++it) {
            int c = it * 256 + wave * 64 + lane;
            int r = c >> 3, s = c & 7;
            int sd = ((s ^ (r & 7)) << 3);
            gload_lds16(A + (size_t)(m0 + r) * K + k0 + sd,
                        &lA[(size_t)(it * 256 + wave * 64) * 8]);
        }
#pragma unroll
        for (int it = 0; it < 2; ++it) {
            int c = it * 256 + wave * 64 + lane;
            int r = c >> 3, s = c & 7;
            int sd = ((s ^ (r & 7)) << 3);
            gload_lds16(Bt + (size_t)(n0 + r) * K + k0 + sd,
                        &lB[(size_t)(it * 256 + wave * 64) * 8]);
        }
        __syncthreads();
#pragma unroll
        for (int kk = 0; kk < 2; ++kk) {
            bf16x8 af[4], bf[2];
#pragma unroll
            for (int mi = 0; mi < 4; ++mi) {
                int row = wm + mi * 16 + l15;
                af[mi] = *(const bf16x8*)(&lA[row * 64 + (((kk * 4 + l4) ^ (row & 7)) << 3)]);
            }
#pragma unroll
            for (int ni = 0; ni < 2; ++ni) {
                int row = wn + ni * 16 + l15;
                bf[ni] = *(const bf16x8*)(&lB[row * 64 + (((kk * 4 + l4) ^ (row & 7)) << 3)]);
            }
#pragma unroll
            for (int mi = 0; mi < 4; ++mi)
#pragma unroll
                for (int ni = 0; ni < 2; ++ni)
                    acc[mi][ni] = mfma16(af[mi], bf[ni], acc[mi][ni]);
        }
        __syncthreads();
    }
#pragma unroll
    for (int mi = 0; mi < 4; ++mi)
#pragma unroll
        for (int ni = 0; ni < 2; ++ni)
#pragma unroll
            for (int i = 0; i < 4; ++i) {
                int r = m0 + wm + mi * 16 + l4 * 4 + i;
                int cc = n0 + wn + ni * 16 + l15;
                C[(size_t)r * N + cc] = acc[mi][ni][i];
            }
}

// ---------- sin/cos table: tab[0..65535]=cos(t,d), tab[65536..]=sin ----------
__global__ void rope_tab(float* __restrict__ tab) {
    int i = blockIdx.x * 256 + threadIdx.x;   // 65536 = 2048 t x 32 d
    int t = i >> 5, d = i & 31;
    float invf = powf(10000.0f, -(float)d / 32.0f);
    float ang = (float)t * invf;
    tab[i] = cosf(ang);
    tab[i + 65536] = sinf(ang);
}

__device__ __forceinline__ void load64bf(const u16* p, float* v) {
#pragma unroll
    for (int j = 0; j < 8; ++j) {
        uint4 w = *(const uint4*)(p + j * 8);
        unsigned ws[4] = { w.x, w.y, w.z, w.w };
#pragma unroll
        for (int t = 0; t < 4; ++t) {
            union { unsigned u; float f; } a, b;
            a.u = (ws[t] & 0xFFFFu) << 16;
            b.u = ws[t] & 0xFFFF0000u;
            v[j * 8 + 2 * t] = a.f;
            v[j * 8 + 2 * t + 1] = b.f;
        }
    }
}

// ---------- RoPE + pack: C1[4096][3072] bf16 -> qb (pre-scaled), kb, vt ----------
__global__ void rope_pack(const u16* __restrict__ C1, const float* __restrict__ tab,
                          u16* __restrict__ qb, u16* __restrict__ kb, u16* __restrict__ vt) {
    const float SC = 0.18033688011112042f;   // 0.125 * log2(e)
    int g = blockIdx.x * 256 + threadIdx.x;   // 65536
    int bh = g >> 11;
    int tq = g & 2047;
    int b = bh >> 4, h = bh & 15;
    const u16* base = C1 + (size_t)(b * 2048 + tq) * 3072 + h * 64;

    float cs[32], sn[32];
    const float* tc = tab + tq * 32;
    const float* ts = tab + 65536 + tq * 32;
#pragma unroll
    for (int j = 0; j < 8; ++j) {
        *(float4*)(&cs[j * 4]) = *(const float4*)(tc + j * 4);
        *(float4*)(&sn[j * 4]) = *(const float4*)(ts + j * 4);
    }
    float v[64];
    // ---- q (scaled) ----
    load64bf(base, v);
#pragma unroll
    for (int d = 0; d < 32; ++d) {
        float a = v[d], bb = v[d + 32];
        v[d] = (a * cs[d] - bb * sn[d]) * SC;
        v[d + 32] = (bb * cs[d] + a * sn[d]) * SC;
    }
    {
        u16* dst = qb + ((size_t)bh * 2048 + tq) * 64;
#pragma unroll
        for (int j = 0; j < 8; ++j) {
            uint4 pk;
            pk.x = pack2(v[j * 8 + 0], v[j * 8 + 1]);
            pk.y = pack2(v[j * 8 + 2], v[j * 8 + 3]);
            pk.z = pack2(v[j * 8 + 4], v[j * 8 + 5]);
            pk.w = pack2(v[j * 8 + 6], v[j * 8 + 7]);
            *(uint4*)(dst + j * 8) = pk;
        }
    }
    // ---- k ----
    load64bf(base + 1024, v);
#pragma unroll
    for (int d = 0; d < 32; ++d) {
        float a = v[d], bb = v[d + 32];
        v[d] = a * cs[d] - bb * sn[d];
        v[d + 32] = bb * cs[d] + a * sn[d];
    }
    {
        u16* dst = kb + ((size_t)bh * 2048 + tq) * 64;
#pragma unroll
        for (int j = 0; j < 8; ++j) {
            uint4 pk;
            pk.x = pack2(v[j * 8 + 0], v[j * 8 + 1]);
            pk.y = pack2(v[j * 8 + 2], v[j * 8 + 3]);
            pk.z = pack2(v[j * 8 + 4], v[j * 8 + 5]);
            pk.w = pack2(v[j * 8 + 6], v[j * 8 + 7]);
            *(uint4*)(dst + j * 8) = pk;
        }
    }
    // ---- v (transposed store: vt[bh][dh][t]) ----
    load64bf(base + 2048, v);
#pragma unroll
    for (int d = 0; d < 64; ++d)
        vt[((size_t)bh * 64 + d) * 2048 + tq] = f2bf(v[d]);
}

// ---------- causal flash attention v10: unpaired 4-wave blocks, balanced XCD map ----------
// grid 1024 blocks x 256 thr; block -> (bh, qt) via: xcd=orig&7, p=orig>>3,
// layer=p>>5, cu=p&31; bh=xcd*4+layer (XCD owns 4 heads -> K/V L2-resident);
// qt = layer&1 ? cu : 31-cu (co-resident blocks on a CU sum to constant work).
// Per-iter compute verbatim from flash9 (pi-scramble QK, zero-shuffle P->PV).
__global__ __launch_bounds__(256, 4) void flash10(const u16* __restrict__ qb,
                                                  const u16* __restrict__ kb,
                                                  const u16* __restrict__ vt,
                                                  u16* __restrict__ ao) {
    __shared__ u16 lK[2][64 * 64];   // [kv][d], f_K-XOR-swizzled 16B slots
    __shared__ u16 lV[2][64 * 64];   // [d][kv], row&7-XOR-swizzled 16B slots
    const int orig = blockIdx.x;
    const int xcd = orig & 7, p = orig >> 3;
    const int cup = p & 31, layer = p >> 5;
    const int bh = xcd * 4 + layer;
    const int qt = (layer & 1) ? cup : 31 - cup;
    const int b = bh >> 4, h = bh & 15;
    const int tid = threadIdx.x;
    const int wave = tid >> 6, lane = tid & 63;
    const int l15 = lane & 15, l4 = lane >> 4;
    const u16* qptr = qb + (size_t)bh * 2048 * 64;
    const u16* kptr = kb + (size_t)bh * 2048 * 64;
    const u16* vptr = vt + (size_t)bh * 64 * 2048;

    // Q fragments (B-operand: col=l15=q, k=l4*8+j=d)
    const int qrow = qt * 64 + wave * 16 + l15;
    bf16x8 q0 = *(const bf16x8*)(qptr + (size_t)qrow * 64 + l4 * 8);
    bf16x8 q1 = *(const bf16x8*)(qptr + (size_t)qrow * 64 + 32 + l4 * 8);

    f32x4 O[4] = {};
    float mrun = -INFINITY, lrun = 0.f;

    int idxO[4];
#pragma unroll
    for (int i = 0; i < 4; ++i) idxO[i] = (lane & 48) | (l4 * 4 + i);

    // pi base row for this lane's A-operand reads (QK)
    const int r0q = ((l15 >> 2) << 3) | (l15 & 3);

    // staging: 4 waves cover 512 K-chunks + 512 V-chunks (2 each per thread)
    auto stage = [&](int buf, int kv0) {
#pragma unroll
        for (int it = 0; it < 2; ++it) {
            int cb = wave * 64 + it * 256;       // wave-uniform chunk base
            int c = cb + lane;
            int r = c >> 3, s = c & 7;
            int fK = (r & 3) | ((r >> 1) & 4);
            gload_lds16(kptr + (size_t)(kv0 + r) * 64 + ((s ^ fK) << 3), &lK[buf][cb * 8]);
            gload_lds16(vptr + (size_t)r * 2048 + kv0 + ((s ^ (r & 7)) << 3), &lV[buf][cb * 8]);
        }
    };
    auto ldK = [&](int buf, int row, int slot) -> bf16x8 {
        int f = (row & 3) | ((row >> 1) & 4);
        return *(const bf16x8*)(&lK[buf][row * 64 + ((slot ^ f) << 3)]);
    };
    auto ldV = [&](int buf, int row, int slot) -> bf16x8 {
        return *(const bf16x8*)(&lV[buf][row * 64 + ((slot ^ (row & 7)) << 3)]);
    };

    // softmax + pack-to-A-frag; p[m][i] at kv = kv0 + 32(m>>1) + 8*l4 + 4(m&1) + i
    auto smpack = [&](f32x4 S[4], float& mr, float& lr, f32x4 Ov[4],
                      bf16x8 af[2], bool diag, int kv0, int qr) {
        float p2[4][4];
#pragma unroll
        for (int m = 0; m < 4; ++m)
#pragma unroll
            for (int i = 0; i < 4; ++i) {
                float s = S[m][i];
                if (diag && (kv0 + ((m >> 1) << 5) + (l4 << 3) + ((m & 1) << 2) + i > qr))
                    s = -INFINITY;
                p2[m][i] = s;
            }
        float m = p2[0][0];
#pragma unroll
        for (int c = 0; c < 4; ++c)
#pragma unroll
            for (int i = 0; i < 4; ++i) m = fmaxf(m, p2[c][i]);
        m = fmaxf(m, __shfl_xor(m, 16));
        m = fmaxf(m, __shfl_xor(m, 32));
        float mnew = fmaxf(mr, m);
        float corr = __builtin_amdgcn_exp2f(mr - mnew);
        float rs = 0.f;
#pragma unroll
        for (int c = 0; c < 4; ++c)
#pragma unroll
            for (int i = 0; i < 4; ++i) { p2[c][i] = __builtin_amdgcn_exp2f(p2[c][i] - mnew); rs += p2[c][i]; }
        rs += __shfl_xor(rs, 16);
        rs += __shfl_xor(rs, 32);
        lr = lr * corr + rs;
        mr = mnew;
#pragma unroll
        for (int i = 0; i < 4; ++i) {
            float cf = __shfl(corr, idxO[i]);
#pragma unroll
            for (int c2 = 0; c2 < 4; ++c2) Ov[c2][i] *= cf;
        }
        unsigned w[4][2];
#pragma unroll
        for (int c = 0; c < 4; ++c) {
            asm("v_cvt_pk_bf16_f32 %0, %1, %2" : "=v"(w[c][0]) : "v"(p2[c][0]), "v"(p2[c][1]));
            asm("v_cvt_pk_bf16_f32 %0, %1, %2" : "=v"(w[c][1]) : "v"(p2[c][2]), "v"(p2[c][3]));
        }
#pragma unroll
        for (int ks = 0; ks < 2; ++ks) {
            union { unsigned u[4]; bf16x8 v; } cvt;
            cvt.u[0] = w[2 * ks][0];
            cvt.u[1] = w[2 * ks][1];
            cvt.u[2] = w[2 * ks + 1][0];
            cvt.u[3] = w[2 * ks + 1][1];
            af[ks] = cvt.v;
        }
    };

    stage(0, 0);
    for (int kvb = 0; kvb <= qt; ++kvb) {
        const int cur = kvb & 1;
        const int kv0 = kvb * 64;
        if (kvb < qt) {
            stage(cur ^ 1, kv0 + 64);
            asm volatile("s_waitcnt vmcnt(4)" ::: "memory");
        } else {
            asm volatile("s_waitcnt vmcnt(0)" ::: "memory");
        }
        __builtin_amdgcn_s_barrier();
        __builtin_amdgcn_sched_barrier(0);

        // QK^T swapped with pi-scrambled A-rows
        f32x4 S[4] = {};
#pragma unroll
        for (int mm = 0; mm < 4; ++mm) {
            int row = r0q + ((mm >> 1) << 5) + ((mm & 1) << 2);
            bf16x8 kf0 = ldK(cur, row, l4);
            bf16x8 kf1 = ldK(cur, row, 4 + l4);
            S[mm] = mfma16(kf0, q0, S[mm]);
            S[mm] = mfma16(kf1, q1, S[mm]);
        }
        bf16x8 af[2];
        smpack(S, mrun, lrun, O, af, kvb == qt, kv0, qrow);
#pragma unroll
        for (int ks = 0; ks < 2; ++ks)
#pragma unroll
            for (int c2 = 0; c2 < 4; ++c2) {
                bf16x8 vf = ldV(cur, c2 * 16 + l15, ks * 4 + l4);
                O[c2] = mfma16(af[ks], vf, O[c2]);
            }
        __builtin_amdgcn_s_barrier();   // protect buffer overwrite by next stage
    }

    // epilogue: O rows are q'=l4*4+i, cols d=c2*16+l15
#pragma unroll
    for (int i = 0; i < 4; ++i) {
        float lv = __shfl(lrun, idxO[i]);
        float rcp = 1.f / lv;
        int qg = qt * 64 + wave * 16 + l4 * 4 + i;
#pragma unroll
        for (int c2 = 0; c2 < 4; ++c2)
            ao[(size_t)(b * 2048 + qg) * 1024 + h * 64 + c2 * 16 + l15] = f2bf(O[c2][i] * rcp);
    }
}

// ---------- launch ----------
extern "C" void kernel_launch(void* const* d_in, const int* in_sizes, int n_in,
                              void* d_out, int out_size, void* d_ws, size_t ws_size,
                              hipStream_t stream) {
    const float* x    = (const float*)d_in[0];   // (2,2048,1024)
    const float* Wqkv = (const float*)d_in[1];   // (1024,3072)
    const float* Wout = (const float*)d_in[2];   // (1024,1024)
    float* out = (float*)d_out;                  // (2,2048,1024)
    char* ws = (char*)d_ws;

    u16*   xb  = (u16*)(ws + 0);            // 8 MB  (4096x1024 bf16)
    u16*   Wtq = (u16*)(ws + 8388608);      // 6 MB  (3072x1024 bf16)
    u16*   Wto = (u16*)(ws + 14680064);     // 2 MB  (1024x1024 bf16)
    u16*   C1b = (u16*)(ws + 16777216);     // 24 MB (4096x3072 bf16)
    u16*   qb  = (u16*)(ws + 67108864);     // 8 MB  (B,H,T,Dh bf16, pre-scaled)
    u16*   kb  = (u16*)(ws + 75497472);     // 8 MB
    u16*   vt  = (u16*)(ws + 83886080);     // 8 MB  (B,H,Dh,T bf16)
    float* tab = (float*)(ws + 92274688);   // 512 KB sin/cos table
    u16*   ao  = (u16*)(ws + 0);            // reuse xb region (GEMM1 done by then)

    cvt_bf16<<<dim3(4096), dim3(256), 0, stream>>>(x, xb);
    transpose_cvt<<<dim3(96, 32), dim3(256), 0, stream>>>(Wqkv, Wtq, 1024, 3072);
    transpose_cvt<<<dim3(32, 32), dim3(256), 0, stream>>>(Wout, Wto, 1024, 1024);
    rope_tab<<<dim3(256), dim3(256), 0, stream>>>(tab);
    gemm_bt<true><<<dim3(24, 32), dim3(256), 0, stream>>>(xb, Wtq, (void*)C1b, 4096, 3072, 1024);
    rope_pack<<<dim3(256), dim3(256), 0, stream>>>(C1b, tab, qb, kb, vt);
    flash10<<<dim3(1024), dim3(256), 0, stream>>>(qb, kb, vt, ao);
    gemm_bt_n64<<<dim3(16, 32), dim3(256), 0, stream>>>(ao, Wto, out, 4096, 1024, 1024);
}

// Round 11
// 131.261 us; speedup vs baseline: 2.1225x; 1.0141x over previous
//
#include <hip/hip_runtime.h>
#include <math.h>

typedef unsigned short u16;
typedef short bf16x8 __attribute__((ext_vector_type(8)));
typedef float f32x4 __attribute__((ext_vector_type(4)));

#define ROPE_SC 0.18033688011112042f   // 0.125 * log2(e)

// ---------- helpers ----------
__device__ __forceinline__ u16 f2bf(float f) {
    union { float f; unsigned u; } x; x.f = f;
    unsigned u = x.u;
    unsigned r = (u + 0x7fffu + ((u >> 16) & 1u)) >> 16;   // RNE, no NaN in data
    return (u16)r;
}
__device__ __forceinline__ unsigned pack2(float a, float b) {
    return (unsigned)f2bf(a) | ((unsigned)f2bf(b) << 16);
}
__device__ __forceinline__ f32x4 mfma16(bf16x8 a, bf16x8 b, f32x4 c) {
    return __builtin_amdgcn_mfma_f32_16x16x32_bf16(a, b, c, 0, 0, 0);
}
__device__ __forceinline__ void gload_lds16(const void* g, void* l) {
    __builtin_amdgcn_global_load_lds((const __attribute__((address_space(1))) void*)g,
                                     (__attribute__((address_space(3))) void*)l,
                                     16, 0, 0);
}

// ---------- fp32 -> bf16 cast (vectorized) ----------
__global__ void cvt_bf16(const float* __restrict__ X, u16* __restrict__ Y) {
    int i = (blockIdx.x * 256 + threadIdx.x) * 4;
    float4 v = *(const float4*)(X + i);
    uint2 o;
    o.x = pack2(v.x, v.y);
    o.y = pack2(v.z, v.w);
    *(uint2*)(Y + i) = o;
}

// ---------- W[R][C] fp32 -> Wt[C][R] bf16 (LDS-tiled transpose) ----------
__global__ void transpose_cvt(const float* __restrict__ W, u16* __restrict__ Wt,
                              int R, int C) {
    __shared__ u16 tile[32][33];
    int tx = threadIdx.x & 31, ty = threadIdx.x >> 5;  // 32 x 8
    int bx = blockIdx.x * 32;
    int by = blockIdx.y * 32;
#pragma unroll
    for (int r = ty; r < 32; r += 8)
        tile[r][tx] = f2bf(W[(size_t)(by + r) * C + bx + tx]);
    __syncthreads();
#pragma unroll
    for (int r = ty; r < 32; r += 8)
        Wt[(size_t)(bx + r) * R + by + tx] = tile[tx][r];
}

// ---------- sin/cos table: tab[0..65535]=cos(t,d), tab[65536..]=sin ----------
__global__ void rope_tab(float* __restrict__ tab) {
    int i = blockIdx.x * 256 + threadIdx.x;   // 65536 = 2048 t x 32 d
    int t = i >> 5, d = i & 31;
    float invf = powf(10000.0f, -(float)d / 32.0f);
    float ang = (float)t * invf;
    tab[i] = cosf(ang);
    tab[i + 65536] = sinf(ang);
}

// ---------- fused QKV GEMM + RoPE + pack epilogue ----------
// C-tile cols decide region: q (rope+SC -> qb), k (rope -> kb), v (transpose -> vt).
// RoPE pair (d, d+32) = (acc[mi][ni], acc[mi][ni+2]) for ni in {0,1} - same thread.
__global__ __launch_bounds__(256) void gemm_qkv(const u16* __restrict__ A,
                                                const u16* __restrict__ Bt,
                                                const float* __restrict__ tab,
                                                u16* __restrict__ qb,
                                                u16* __restrict__ kb,
                                                u16* __restrict__ vt,
                                                int M, int N, int K) {
    __shared__ u16 lA[128 * 64];
    __shared__ u16 lB[128 * 64];
    const int tid = threadIdx.x;
    const int wave = tid >> 6, lane = tid & 63;
    const int l15 = lane & 15, l4 = lane >> 4;
    const int nwg = gridDim.x * gridDim.y;
    const int orig = blockIdx.y * gridDim.x + blockIdx.x;
    const int swz = (orig & 7) * (nwg >> 3) + (orig >> 3);
    const int m0 = (swz / gridDim.x) * 128, n0 = (swz % gridDim.x) * 128;
    const int wm = (wave >> 1) * 64, wn = (wave & 1) * 64;
    f32x4 acc[4][4] = {};
    for (int k0 = 0; k0 < K; k0 += 64) {
#pragma unroll
        for (int it = 0; it < 4; ++it) {
            int c = it * 256 + wave * 64 + lane;
            int r = c >> 3, s = c & 7;
            int sd = ((s ^ (r & 7)) << 3);
            gload_lds16(A + (size_t)(m0 + r) * K + k0 + sd,
                        &lA[(size_t)(it * 256 + wave * 64) * 8]);
            gload_lds16(Bt + (size_t)(n0 + r) * K + k0 + sd,
                        &lB[(size_t)(it * 256 + wave * 64) * 8]);
        }
        __syncthreads();
#pragma unroll
        for (int kk = 0; kk < 2; ++kk) {
            bf16x8 af[4], bf[4];
#pragma unroll
            for (int mi = 0; mi < 4; ++mi) {
                int row = wm + mi * 16 + l15;
                af[mi] = *(const bf16x8*)(&lA[row * 64 + (((kk * 4 + l4) ^ (row & 7)) << 3)]);
            }
#pragma unroll
            for (int ni = 0; ni < 4; ++ni) {
                int row = wn + ni * 16 + l15;
                bf[ni] = *(const bf16x8*)(&lB[row * 64 + (((kk * 4 + l4) ^ (row & 7)) << 3)]);
            }
#pragma unroll
            for (int mi = 0; mi < 4; ++mi)
#pragma unroll
                for (int ni = 0; ni < 4; ++ni)
                    acc[mi][ni] = mfma16(af[mi], bf[ni], acc[mi][ni]);
        }
        __syncthreads();
    }
    // ---- fused epilogue ----
    const int colg = n0 + wn;            // wave-uniform 64-col group base
    const int region = colg >> 10;       // 0=q, 1=k, 2=v
    const int h = (colg & 1023) >> 6;    // head within region
    if (region == 2) {
        // V: store transposed vt[(b*16+h)*64 + dcol][tq], 4 consecutive t packed
#pragma unroll
        for (int mi = 0; mi < 4; ++mi) {
            int t0 = m0 + wm + mi * 16 + l4 * 4;
            int b = t0 >> 11, tq0 = t0 & 2047;
#pragma unroll
            for (int ni = 0; ni < 4; ++ni) {
                int dcol = ni * 16 + l15;
                uint2 pk;
                pk.x = pack2(acc[mi][ni][0], acc[mi][ni][1]);
                pk.y = pack2(acc[mi][ni][2], acc[mi][ni][3]);
                *(uint2*)(vt + ((size_t)(b * 16 + h) * 64 + dcol) * 2048 + tq0) = pk;
            }
        }
    } else {
        const float sc = (region == 0) ? ROPE_SC : 1.0f;
        u16* dst = (region == 0) ? qb : kb;
#pragma unroll
        for (int mi = 0; mi < 4; ++mi)
#pragma unroll
            for (int i = 0; i < 4; ++i) {
                int t = m0 + wm + mi * 16 + l4 * 4 + i;
                int b = t >> 11, tq = t & 2047;
                const float* tcb = tab + tq * 32;
                const float* tsb = tab + 65536 + tq * 32;
                size_t base = ((size_t)(b * 16 + h) * 2048 + tq) * 64;
#pragma unroll
                for (int ni = 0; ni < 2; ++ni) {
                    int d32 = ni * 16 + l15;
                    float cs = tcb[d32], sn = tsb[d32];
                    float a = acc[mi][ni][i], bb = acc[mi][ni + 2][i];
                    dst[base + d32]      = f2bf((a * cs - bb * sn) * sc);
                    dst[base + d32 + 32] = f2bf((bb * cs + a * sn) * sc);
                }
            }
    }
}

// ---------- GEMM 128x64 tile (final proj): grid (N/64, M/128), T1 swizzle ----------
__global__ __launch_bounds__(256) void gemm_bt_n64(const u16* __restrict__ A,
                                                   const u16* __restrict__ Bt,
                                                   float* __restrict__ C,
                                                   int M, int N, int K) {
    __shared__ u16 lA[128 * 64];
    __shared__ u16 lB[64 * 64];
    const int tid = threadIdx.x;
    const int wave = tid >> 6, lane = tid & 63;
    const int l15 = lane & 15, l4 = lane >> 4;
    const int nwg = gridDim.x * gridDim.y;
    const int orig = blockIdx.y * gridDim.x + blockIdx.x;
    const int swz = (orig & 7) * (nwg >> 3) + (orig >> 3);
    const int m0 = (swz / gridDim.x) * 128, n0 = (swz % gridDim.x) * 64;
    const int wm = (wave >> 1) * 64, wn = (wave & 1) * 32;
    f32x4 acc[4][2] = {};
    for (int k0 = 0; k0 < K; k0 += 64) {
#pragma unroll
        for (int it = 0; it < 4; ++it) {
            int c = it * 256 + wave * 64 + lane;
            int r = c >> 3, s = c & 7;
            int sd = ((s ^ (r & 7)) << 3);
            gload_lds16(A + (size_t)(m0 + r) * K + k0 + sd,
                        &lA[(size_t)(it * 256 + wave * 64) * 8]);
        }
#pragma unroll
        for (int it = 0; it < 2; ++it) {
            int c = it * 256 + wave * 64 + lane;
            int r = c >> 3, s = c & 7;
            int sd = ((s ^ (r & 7)) << 3);
            gload_lds16(Bt + (size_t)(n0 + r) * K + k0 + sd,
                        &lB[(size_t)(it * 256 + wave * 64) * 8]);
        }
        __syncthreads();
#pragma unroll
        for (int kk = 0; kk < 2; ++kk) {
            bf16x8 af[4], bf[2];
#pragma unroll
            for (int mi = 0; mi < 4; ++mi) {
                int row = wm + mi * 16 + l15;
                af[mi] = *(const bf16x8*)(&lA[row * 64 + (((kk * 4 + l4) ^ (row & 7)) << 3)]);
            }
#pragma unroll
            for (int ni = 0; ni < 2; ++ni) {
                int row = wn + ni * 16 + l15;
                bf[ni] = *(const bf16x8*)(&lB[row * 64 + (((kk * 4 + l4) ^ (row & 7)) << 3)]);
            }
#pragma unroll
            for (int mi = 0; mi < 4; ++mi)
#pragma unroll
                for (int ni = 0; ni < 2; ++ni)
                    acc[mi][ni] = mfma16(af[mi], bf[ni], acc[mi][ni]);
        }
        __syncthreads();
    }
#pragma unroll
    for (int mi = 0; mi < 4; ++mi)
#pragma unroll
        for (int ni = 0; ni < 2; ++ni)
#pragma unroll
            for (int i = 0; i < 4; ++i) {
                int r = m0 + wm + mi * 16 + l4 * 4 + i;
                int cc = n0 + wn + ni * 16 + l15;
                C[(size_t)r * N + cc] = acc[mi][ni][i];
            }
}

// ---------- causal flash attention v11: 32 q-rows/wave (128-row tiles) ----------
// grid 512: xcd=orig&7 owns 4 heads; p=orig>>3 in 0..63; bh=xcd*4+(p&3);
// j = (p<32) ? (p>>2)&7 : 15-((p>>2)&7)  => CU c hosts {j, 15-j} of same bh.
// Each wave: rows j*128 + wave*32 + g*16 (g=0,1); K/V LDS reads shared across g.
__global__ __launch_bounds__(256, 2) void flash11(const u16* __restrict__ qb,
                                                  const u16* __restrict__ kb,
                                                  const u16* __restrict__ vt,
                                                  u16* __restrict__ ao) {
    __shared__ u16 lK[2][64 * 64];   // [kv][d], f_K-XOR-swizzled 16B slots
    __shared__ u16 lV[2][64 * 64];   // [d][kv], row&7-XOR-swizzled 16B slots
    const int orig = blockIdx.x;
    const int xcd = orig & 7, p = orig >> 3;
    const int bh = xcd * 4 + (p & 3);
    const int j = (p < 32) ? ((p >> 2) & 7) : 15 - ((p >> 2) & 7);
    const int b = bh >> 4, h = bh & 15;
    const int tid = threadIdx.x;
    const int wave = tid >> 6, lane = tid & 63;
    const int l15 = lane & 15, l4 = lane >> 4;
    const int niter = 2 * (j + 1);
    const u16* qptr = qb + (size_t)bh * 2048 * 64;
    const u16* kptr = kb + (size_t)bh * 2048 * 64;
    const u16* vptr = vt + (size_t)bh * 64 * 2048;

    // Q fragments for two 16-row groups (B-operand: col=l15=q, k=l4*8+jj=d)
    int qrow[2];
    bf16x8 q0[2], q1[2];
#pragma unroll
    for (int g = 0; g < 2; ++g) {
        qrow[g] = j * 128 + wave * 32 + g * 16 + l15;
        q0[g] = *(const bf16x8*)(qptr + (size_t)qrow[g] * 64 + l4 * 8);
        q1[g] = *(const bf16x8*)(qptr + (size_t)qrow[g] * 64 + 32 + l4 * 8);
    }

    f32x4 O[2][4] = {};
    float mrun[2] = { -INFINITY, -INFINITY }, lrun[2] = { 0.f, 0.f };

    int idxO[4];
#pragma unroll
    for (int i = 0; i < 4; ++i) idxO[i] = (lane & 48) | (l4 * 4 + i);

    const int r0q = ((l15 >> 2) << 3) | (l15 & 3);   // pi base row

    auto stage = [&](int buf, int kv0) {
#pragma unroll
        for (int it = 0; it < 2; ++it) {
            int cb = wave * 64 + it * 256;
            int c = cb + lane;
            int r = c >> 3, s = c & 7;
            int fK = (r & 3) | ((r >> 1) & 4);
            gload_lds16(kptr + (size_t)(kv0 + r) * 64 + ((s ^ fK) << 3), &lK[buf][cb * 8]);
            gload_lds16(vptr + (size_t)r * 2048 + kv0 + ((s ^ (r & 7)) << 3), &lV[buf][cb * 8]);
        }
    };
    auto ldK = [&](int buf, int row, int slot) -> bf16x8 {
        int f = (row & 3) | ((row >> 1) & 4);
        return *(const bf16x8*)(&lK[buf][row * 64 + ((slot ^ f) << 3)]);
    };
    auto ldV = [&](int buf, int row, int slot) -> bf16x8 {
        return *(const bf16x8*)(&lV[buf][row * 64 + ((slot ^ (row & 7)) << 3)]);
    };

    // softmax + pack-to-A-frag (verbatim flash10); p[m][i] at
    // kv = kv0 + 32(m>>1) + 8*l4 + 4(m&1) + i
    auto smpack = [&](f32x4 S[4], float& mr, float& lr, f32x4 Ov[4],
                      bf16x8 af[2], bool diag, int kv0, int qr) {
        float p2[4][4];
#pragma unroll
        for (int m = 0; m < 4; ++m)
#pragma unroll
            for (int i = 0; i < 4; ++i) {
                float s = S[m][i];
                if (diag && (kv0 + ((m >> 1) << 5) + (l4 << 3) + ((m & 1) << 2) + i > qr))
                    s = -INFINITY;
                p2[m][i] = s;
            }
        float m = p2[0][0];
#pragma unroll
        for (int c = 0; c < 4; ++c)
#pragma unroll
            for (int i = 0; i < 4; ++i) m = fmaxf(m, p2[c][i]);
        m = fmaxf(m, __shfl_xor(m, 16));
        m = fmaxf(m, __shfl_xor(m, 32));
        float mnew = fmaxf(mr, m);
        float corr = __builtin_amdgcn_exp2f(mr - mnew);
        float rs = 0.f;
#pragma unroll
        for (int c = 0; c < 4; ++c)
#pragma unroll
            for (int i = 0; i < 4; ++i) { p2[c][i] = __builtin_amdgcn_exp2f(p2[c][i] - mnew); rs += p2[c][i]; }
        rs += __shfl_xor(rs, 16);
        rs += __shfl_xor(rs, 32);
        lr = lr * corr + rs;
        mr = mnew;
#pragma unroll
        for (int i = 0; i < 4; ++i) {
            float cf = __shfl(corr, idxO[i]);
#pragma unroll
            for (int c2 = 0; c2 < 4; ++c2) Ov[c2][i] *= cf;
        }
        unsigned w[4][2];
#pragma unroll
        for (int c = 0; c < 4; ++c) {
            asm("v_cvt_pk_bf16_f32 %0, %1, %2" : "=v"(w[c][0]) : "v"(p2[c][0]), "v"(p2[c][1]));
            asm("v_cvt_pk_bf16_f32 %0, %1, %2" : "=v"(w[c][1]) : "v"(p2[c][2]), "v"(p2[c][3]));
        }
#pragma unroll
        for (int ks = 0; ks < 2; ++ks) {
            union { unsigned u[4]; bf16x8 v; } cvt;
            cvt.u[0] = w[2 * ks][0];
            cvt.u[1] = w[2 * ks][1];
            cvt.u[2] = w[2 * ks + 1][0];
            cvt.u[3] = w[2 * ks + 1][1];
            af[ks] = cvt.v;
        }
    };

    stage(0, 0);
    for (int kvb = 0; kvb < niter; ++kvb) {
        const int cur = kvb & 1;
        const int kv0 = kvb * 64;
        if (kvb < niter - 1) {
            stage(cur ^ 1, kv0 + 64);
            asm volatile("s_waitcnt vmcnt(4)" ::: "memory");
        } else {
            asm volatile("s_waitcnt vmcnt(0)" ::: "memory");
        }
        __builtin_amdgcn_s_barrier();
        __builtin_amdgcn_sched_barrier(0);

        // QK^T swapped, pi-scrambled A-rows; K fragments shared by both q-groups
        f32x4 S0[4] = {}, S1[4] = {};
#pragma unroll
        for (int mm = 0; mm < 4; ++mm) {
            int row = r0q + ((mm >> 1) << 5) + ((mm & 1) << 2);
            bf16x8 kf0 = ldK(cur, row, l4);
            bf16x8 kf1 = ldK(cur, row, 4 + l4);
            S0[mm] = mfma16(kf0, q0[0], S0[mm]);
            S0[mm] = mfma16(kf1, q1[0], S0[mm]);
            S1[mm] = mfma16(kf0, q0[1], S1[mm]);
            S1[mm] = mfma16(kf1, q1[1], S1[mm]);
        }
        const bool diag = (kvb >= niter - 2);
        bf16x8 af0[2], af1[2];
        smpack(S0, mrun[0], lrun[0], O[0], af0, diag, kv0, qrow[0]);
        smpack(S1, mrun[1], lrun[1], O[1], af1, diag, kv0, qrow[1]);
#pragma unroll
        for (int ks = 0; ks < 2; ++ks)
#pragma unroll
            for (int c2 = 0; c2 < 4; ++c2) {
                bf16x8 vf = ldV(cur, c2 * 16 + l15, ks * 4 + l4);
                O[0][c2] = mfma16(af0[ks], vf, O[0][c2]);
                O[1][c2] = mfma16(af1[ks], vf, O[1][c2]);
            }
        __builtin_amdgcn_s_barrier();   // protect buffer overwrite by next stage
    }

    // epilogue: per group, O rows are q'=l4*4+i, cols d=c2*16+l15
#pragma unroll
    for (int g = 0; g < 2; ++g)
#pragma unroll
        for (int i = 0; i < 4; ++i) {
            float lv = __shfl(lrun[g], idxO[i]);
            float rcp = 1.f / lv;
            int qg = j * 128 + wave * 32 + g * 16 + l4 * 4 + i;
#pragma unroll
            for (int c2 = 0; c2 < 4; ++c2)
                ao[(size_t)(b * 2048 + qg) * 1024 + h * 64 + c2 * 16 + l15] = f2bf(O[g][c2][i] * rcp);
        }
}

// ---------- launch ----------
extern "C" void kernel_launch(void* const* d_in, const int* in_sizes, int n_in,
                              void* d_out, int out_size, void* d_ws, size_t ws_size,
                              hipStream_t stream) {
    const float* x    = (const float*)d_in[0];   // (2,2048,1024)
    const float* Wqkv = (const float*)d_in[1];   // (1024,3072)
    const float* Wout = (const float*)d_in[2];   // (1024,1024)
    float* out = (float*)d_out;                  // (2,2048,1024)
    char* ws = (char*)d_ws;

    u16*   xb  = (u16*)(ws + 0);            // 8 MB  (4096x1024 bf16)
    u16*   Wtq = (u16*)(ws + 8388608);      // 6 MB  (3072x1024 bf16)
    u16*   Wto = (u16*)(ws + 14680064);     // 2 MB  (1024x1024 bf16)
    u16*   qb  = (u16*)(ws + 67108864);     // 8 MB  (B,H,T,Dh bf16, pre-scaled)
    u16*   kb  = (u16*)(ws + 75497472);     // 8 MB
    u16*   vt  = (u16*)(ws + 83886080);     // 8 MB  (B,H,Dh,T bf16)
    float* tab = (float*)(ws + 92274688);   // 512 KB sin/cos table
    u16*   ao  = (u16*)(ws + 0);            // reuse xb region (gemm_qkv done by then)

    cvt_bf16<<<dim3(4096), dim3(256), 0, stream>>>(x, xb);
    transpose_cvt<<<dim3(96, 32), dim3(256), 0, stream>>>(Wqkv, Wtq, 1024, 3072);
    transpose_cvt<<<dim3(32, 32), dim3(256), 0, stream>>>(Wout, Wto, 1024, 1024);
    rope_tab<<<dim3(256), dim3(256), 0, stream>>>(tab);
    gemm_qkv<<<dim3(24, 32), dim3(256), 0, stream>>>(xb, Wtq, tab, qb, kb, vt, 4096, 3072, 1024);
    flash11<<<dim3(512), dim3(256), 0, stream>>>(qb, kb, vt, ao);
    gemm_bt_n64<<<dim3(16, 32), dim3(256), 0, stream>>>(ao, Wto, out, 4096, 1024, 1024);
}

// Round 12
// 110.791 us; speedup vs baseline: 2.5146x; 1.1848x over previous
//
#include <hip/hip_runtime.h>
#include <math.h>

typedef unsigned short u16;
typedef short bf16x8 __attribute__((ext_vector_type(8)));
typedef float f32x4 __attribute__((ext_vector_type(4)));

#define ROPE_SC 0.18033688011112042f   // 0.125 * log2(e)

// ---------- helpers ----------
__device__ __forceinline__ u16 f2bf(float f) {
    union { float f; unsigned u; } x; x.f = f;
    unsigned u = x.u;
    unsigned r = (u + 0x7fffu + ((u >> 16) & 1u)) >> 16;   // RNE, no NaN in data
    return (u16)r;
}
__device__ __forceinline__ unsigned pack2(float a, float b) {
    return (unsigned)f2bf(a) | ((unsigned)f2bf(b) << 16);
}
__device__ __forceinline__ f32x4 mfma16(bf16x8 a, bf16x8 b, f32x4 c) {
    return __builtin_amdgcn_mfma_f32_16x16x32_bf16(a, b, c, 0, 0, 0);
}
__device__ __forceinline__ void gload_lds16(const void* g, void* l) {
    __builtin_amdgcn_global_load_lds((const __attribute__((address_space(1))) void*)g,
                                     (__attribute__((address_space(3))) void*)l,
                                     16, 0, 0);
}

// ---------- fp32 -> bf16 cast (vectorized) ----------
__global__ void cvt_bf16(const float* __restrict__ X, u16* __restrict__ Y) {
    int i = (blockIdx.x * 256 + threadIdx.x) * 4;
    float4 v = *(const float4*)(X + i);
    uint2 o;
    o.x = pack2(v.x, v.y);
    o.y = pack2(v.z, v.w);
    *(uint2*)(Y + i) = o;
}

// ---------- W[R][C] fp32 -> Wt[C][R] bf16 (LDS-tiled transpose) ----------
__global__ void transpose_cvt(const float* __restrict__ W, u16* __restrict__ Wt,
                              int R, int C) {
    __shared__ u16 tile[32][33];
    int tx = threadIdx.x & 31, ty = threadIdx.x >> 5;  // 32 x 8
    int bx = blockIdx.x * 32;
    int by = blockIdx.y * 32;
#pragma unroll
    for (int r = ty; r < 32; r += 8)
        tile[r][tx] = f2bf(W[(size_t)(by + r) * C + bx + tx]);
    __syncthreads();
#pragma unroll
    for (int r = ty; r < 32; r += 8)
        Wt[(size_t)(bx + r) * R + by + tx] = tile[tx][r];
}

// ---------- sin/cos table: tab[0..65535]=cos(t,d), tab[65536..]=sin ----------
__global__ void rope_tab(float* __restrict__ tab) {
    int i = blockIdx.x * 256 + threadIdx.x;   // 65536 = 2048 t x 32 d
    int t = i >> 5, d = i & 31;
    float invf = powf(10000.0f, -(float)d / 32.0f);
    float ang = (float)t * invf;
    tab[i] = cosf(ang);
    tab[i + 65536] = sinf(ang);
}

// ---------- fused QKV GEMM + RoPE + pack epilogue, 8 waves (512 thr) ----------
// wave grid 4M x 2N: wm=(wave>>1)*32, wn=(wave&1)*64 -> each wave owns a full
// 64-col head slice, so RoPE pair (d, d+32) = (acc[mi][ni], acc[mi][ni+2]).
__global__ __launch_bounds__(512) void gemm_qkv(const u16* __restrict__ A,
                                                const u16* __restrict__ Bt,
                                                const float* __restrict__ tab,
                                                u16* __restrict__ qb,
                                                u16* __restrict__ kb,
                                                u16* __restrict__ vt,
                                                int M, int N, int K) {
    __shared__ u16 lA[128 * 64];
    __shared__ u16 lB[128 * 64];
    const int tid = threadIdx.x;
    const int wave = tid >> 6, lane = tid & 63;
    const int l15 = lane & 15, l4 = lane >> 4;
    const int nwg = gridDim.x * gridDim.y;
    const int orig = blockIdx.y * gridDim.x + blockIdx.x;
    const int swz = (orig & 7) * (nwg >> 3) + (orig >> 3);
    const int m0 = (swz / gridDim.x) * 128, n0 = (swz % gridDim.x) * 128;
    const int wm = (wave >> 1) * 32, wn = (wave & 1) * 64;
    f32x4 acc[2][4] = {};
    for (int k0 = 0; k0 < K; k0 += 64) {
#pragma unroll
        for (int it = 0; it < 2; ++it) {
            int cb = it * 512 + wave * 64;       // wave-uniform chunk base
            int c = cb + lane;
            int r = c >> 3, s = c & 7;
            int sd = ((s ^ (r & 7)) << 3);       // inverse-swizzled source slot
            gload_lds16(A + (size_t)(m0 + r) * K + k0 + sd, &lA[(size_t)cb * 8]);
            gload_lds16(Bt + (size_t)(n0 + r) * K + k0 + sd, &lB[(size_t)cb * 8]);
        }
        __syncthreads();
#pragma unroll
        for (int kk = 0; kk < 2; ++kk) {
            bf16x8 af[2], bf[4];
#pragma unroll
            for (int mi = 0; mi < 2; ++mi) {
                int row = wm + mi * 16 + l15;
                af[mi] = *(const bf16x8*)(&lA[row * 64 + (((kk * 4 + l4) ^ (row & 7)) << 3)]);
            }
#pragma unroll
            for (int ni = 0; ni < 4; ++ni) {
                int row = wn + ni * 16 + l15;
                bf[ni] = *(const bf16x8*)(&lB[row * 64 + (((kk * 4 + l4) ^ (row & 7)) << 3)]);
            }
#pragma unroll
            for (int mi = 0; mi < 2; ++mi)
#pragma unroll
                for (int ni = 0; ni < 4; ++ni)
                    acc[mi][ni] = mfma16(af[mi], bf[ni], acc[mi][ni]);
        }
        __syncthreads();
    }
    // ---- fused epilogue ----
    const int colg = n0 + wn;            // wave-uniform 64-col group base
    const int region = colg >> 10;       // 0=q, 1=k, 2=v
    const int h = (colg & 1023) >> 6;    // head within region
    if (region == 2) {
        // V: store transposed vt[(b*16+h)*64 + dcol][tq], 4 consecutive t packed
#pragma unroll
        for (int mi = 0; mi < 2; ++mi) {
            int t0 = m0 + wm + mi * 16 + l4 * 4;
            int b = t0 >> 11, tq0 = t0 & 2047;
#pragma unroll
            for (int ni = 0; ni < 4; ++ni) {
                int dcol = ni * 16 + l15;
                uint2 pk;
                pk.x = pack2(acc[mi][ni][0], acc[mi][ni][1]);
                pk.y = pack2(acc[mi][ni][2], acc[mi][ni][3]);
                *(uint2*)(vt + ((size_t)(b * 16 + h) * 64 + dcol) * 2048 + tq0) = pk;
            }
        }
    } else {
        const float sc = (region == 0) ? ROPE_SC : 1.0f;
        u16* dst = (region == 0) ? qb : kb;
#pragma unroll
        for (int mi = 0; mi < 2; ++mi)
#pragma unroll
            for (int i = 0; i < 4; ++i) {
                int t = m0 + wm + mi * 16 + l4 * 4 + i;
                int b = t >> 11, tq = t & 2047;
                const float* tcb = tab + tq * 32;
                const float* tsb = tab + 65536 + tq * 32;
                size_t base = ((size_t)(b * 16 + h) * 2048 + tq) * 64;
#pragma unroll
                for (int ni = 0; ni < 2; ++ni) {
                    int d32 = ni * 16 + l15;
                    float cs = tcb[d32], sn = tsb[d32];
                    float a = acc[mi][ni][i], bb = acc[mi][ni + 2][i];
                    dst[base + d32]      = f2bf((a * cs - bb * sn) * sc);
                    dst[base + d32 + 32] = f2bf((bb * cs + a * sn) * sc);
                }
            }
    }
}

// ---------- GEMM 128x64 tile (final proj), 8 waves: grid (N/64, M/128) ----------
__global__ __launch_bounds__(512) void gemm_bt_n64(const u16* __restrict__ A,
                                                   const u16* __restrict__ Bt,
                                                   float* __restrict__ C,
                                                   int M, int N, int K) {
    __shared__ u16 lA[128 * 64];
    __shared__ u16 lB[64 * 64];
    const int tid = threadIdx.x;
    const int wave = tid >> 6, lane = tid & 63;
    const int l15 = lane & 15, l4 = lane >> 4;
    const int nwg = gridDim.x * gridDim.y;
    const int orig = blockIdx.y * gridDim.x + blockIdx.x;
    const int swz = (orig & 7) * (nwg >> 3) + (orig >> 3);
    const int m0 = (swz / gridDim.x) * 128, n0 = (swz % gridDim.x) * 64;
    const int wm = (wave >> 1) * 32, wn = (wave & 1) * 32;
    f32x4 acc[2][2] = {};
    for (int k0 = 0; k0 < K; k0 += 64) {
#pragma unroll
        for (int it = 0; it < 2; ++it) {
            int cb = it * 512 + wave * 64;
            int c = cb + lane;
            int r = c >> 3, s = c & 7;
            int sd = ((s ^ (r & 7)) << 3);
            gload_lds16(A + (size_t)(m0 + r) * K + k0 + sd, &lA[(size_t)cb * 8]);
        }
        {
            int cb = wave * 64;
            int c = cb + lane;
            int r = c >> 3, s = c & 7;
            int sd = ((s ^ (r & 7)) << 3);
            gload_lds16(Bt + (size_t)(n0 + r) * K + k0 + sd, &lB[(size_t)cb * 8]);
        }
        __syncthreads();
#pragma unroll
        for (int kk = 0; kk < 2; ++kk) {
            bf16x8 af[2], bf[2];
#pragma unroll
            for (int mi = 0; mi < 2; ++mi) {
                int row = wm + mi * 16 + l15;
                af[mi] = *(const bf16x8*)(&lA[row * 64 + (((kk * 4 + l4) ^ (row & 7)) << 3)]);
            }
#pragma unroll
            for (int ni = 0; ni < 2; ++ni) {
                int row = wn + ni * 16 + l15;
                bf[ni] = *(const bf16x8*)(&lB[row * 64 + (((kk * 4 + l4) ^ (row & 7)) << 3)]);
            }
#pragma unroll
            for (int mi = 0; mi < 2; ++mi)
#pragma unroll
                for (int ni = 0; ni < 2; ++ni)
                    acc[mi][ni] = mfma16(af[mi], bf[ni], acc[mi][ni]);
        }
        __syncthreads();
    }
#pragma unroll
    for (int mi = 0; mi < 2; ++mi)
#pragma unroll
        for (int ni = 0; ni < 2; ++ni)
#pragma unroll
            for (int i = 0; i < 4; ++i) {
                int r = m0 + wm + mi * 16 + l4 * 4 + i;
                int cc = n0 + wn + ni * 16 + l15;
                C[(size_t)r * N + cc] = acc[mi][ni][i];
            }
}

// ---------- causal flash attention v10 (R10-proven, verbatim) ----------
// grid 1024 blocks x 256 thr; block -> (bh, qt) via: xcd=orig&7, p=orig>>3,
// layer=p>>5, cu=p&31; bh=xcd*4+layer (XCD owns 4 heads -> K/V L2-resident);
// qt = layer&1 ? cu : 31-cu.
__global__ __launch_bounds__(256, 4) void flash10(const u16* __restrict__ qb,
                                                  const u16* __restrict__ kb,
                                                  const u16* __restrict__ vt,
                                                  u16* __restrict__ ao) {
    __shared__ u16 lK[2][64 * 64];   // [kv][d], f_K-XOR-swizzled 16B slots
    __shared__ u16 lV[2][64 * 64];   // [d][kv], row&7-XOR-swizzled 16B slots
    const int orig = blockIdx.x;
    const int xcd = orig & 7, p = orig >> 3;
    const int cup = p & 31, layer = p >> 5;
    const int bh = xcd * 4 + layer;
    const int qt = (layer & 1) ? cup : 31 - cup;
    const int b = bh >> 4, h = bh & 15;
    const int tid = threadIdx.x;
    const int wave = tid >> 6, lane = tid & 63;
    const int l15 = lane & 15, l4 = lane >> 4;
    const u16* qptr = qb + (size_t)bh * 2048 * 64;
    const u16* kptr = kb + (size_t)bh * 2048 * 64;
    const u16* vptr = vt + (size_t)bh * 64 * 2048;

    const int qrow = qt * 64 + wave * 16 + l15;
    bf16x8 q0 = *(const bf16x8*)(qptr + (size_t)qrow * 64 + l4 * 8);
    bf16x8 q1 = *(const bf16x8*)(qptr + (size_t)qrow * 64 + 32 + l4 * 8);

    f32x4 O[4] = {};
    float mrun = -INFINITY, lrun = 0.f;

    int idxO[4];
#pragma unroll
    for (int i = 0; i < 4; ++i) idxO[i] = (lane & 48) | (l4 * 4 + i);

    const int r0q = ((l15 >> 2) << 3) | (l15 & 3);   // pi base row

    auto stage = [&](int buf, int kv0) {
#pragma unroll
        for (int it = 0; it < 2; ++it) {
            int cb = wave * 64 + it * 256;       // wave-uniform chunk base
            int c = cb + lane;
            int r = c >> 3, s = c & 7;
            int fK = (r & 3) | ((r >> 1) & 4);
            gload_lds16(kptr + (size_t)(kv0 + r) * 64 + ((s ^ fK) << 3), &lK[buf][cb * 8]);
            gload_lds16(vptr + (size_t)r * 2048 + kv0 + ((s ^ (r & 7)) << 3), &lV[buf][cb * 8]);
        }
    };
    auto ldK = [&](int buf, int row, int slot) -> bf16x8 {
        int f = (row & 3) | ((row >> 1) & 4);
        return *(const bf16x8*)(&lK[buf][row * 64 + ((slot ^ f) << 3)]);
    };
    auto ldV = [&](int buf, int row, int slot) -> bf16x8 {
        return *(const bf16x8*)(&lV[buf][row * 64 + ((slot ^ (row & 7)) << 3)]);
    };

    // softmax + pack-to-A-frag; p[m][i] at kv = kv0 + 32(m>>1) + 8*l4 + 4(m&1) + i
    auto smpack = [&](f32x4 S[4], float& mr, float& lr, f32x4 Ov[4],
                      bf16x8 af[2], bool diag, int kv0, int qr) {
        float p2[4][4];
#pragma unroll
        for (int m = 0; m < 4; ++m)
#pragma unroll
            for (int i = 0; i < 4; ++i) {
                float s = S[m][i];
                if (diag && (kv0 + ((m >> 1) << 5) + (l4 << 3) + ((m & 1) << 2) + i > qr))
                    s = -INFINITY;
                p2[m][i] = s;
            }
        float m = p2[0][0];
#pragma unroll
        for (int c = 0; c < 4; ++c)
#pragma unroll
            for (int i = 0; i < 4; ++i) m = fmaxf(m, p2[c][i]);
        m = fmaxf(m, __shfl_xor(m, 16));
        m = fmaxf(m, __shfl_xor(m, 32));
        float mnew = fmaxf(mr, m);
        float corr = __builtin_amdgcn_exp2f(mr - mnew);
        float rs = 0.f;
#pragma unroll
        for (int c = 0; c < 4; ++c)
#pragma unroll
            for (int i = 0; i < 4; ++i) { p2[c][i] = __builtin_amdgcn_exp2f(p2[c][i] - mnew); rs += p2[c][i]; }
        rs += __shfl_xor(rs, 16);
        rs += __shfl_xor(rs, 32);
        lr = lr * corr + rs;
        mr = mnew;
#pragma unroll
        for (int i = 0; i < 4; ++i) {
            float cf = __shfl(corr, idxO[i]);
#pragma unroll
            for (int c2 = 0; c2 < 4; ++c2) Ov[c2][i] *= cf;
        }
        unsigned w[4][2];
#pragma unroll
        for (int c = 0; c < 4; ++c) {
            asm("v_cvt_pk_bf16_f32 %0, %1, %2" : "=v"(w[c][0]) : "v"(p2[c][0]), "v"(p2[c][1]));
            asm("v_cvt_pk_bf16_f32 %0, %1, %2" : "=v"(w[c][1]) : "v"(p2[c][2]), "v"(p2[c][3]));
        }
#pragma unroll
        for (int ks = 0; ks < 2; ++ks) {
            union { unsigned u[4]; bf16x8 v; } cvt;
            cvt.u[0] = w[2 * ks][0];
            cvt.u[1] = w[2 * ks][1];
            cvt.u[2] = w[2 * ks + 1][0];
            cvt.u[3] = w[2 * ks + 1][1];
            af[ks] = cvt.v;
        }
    };

    stage(0, 0);
    for (int kvb = 0; kvb <= qt; ++kvb) {
        const int cur = kvb & 1;
        const int kv0 = kvb * 64;
        if (kvb < qt) {
            stage(cur ^ 1, kv0 + 64);
            asm volatile("s_waitcnt vmcnt(4)" ::: "memory");
        } else {
            asm volatile("s_waitcnt vmcnt(0)" ::: "memory");
        }
        __builtin_amdgcn_s_barrier();
        __builtin_amdgcn_sched_barrier(0);

        // QK^T swapped with pi-scrambled A-rows
        f32x4 S[4] = {};
#pragma unroll
        for (int mm = 0; mm < 4; ++mm) {
            int row = r0q + ((mm >> 1) << 5) + ((mm & 1) << 2);
            bf16x8 kf0 = ldK(cur, row, l4);
            bf16x8 kf1 = ldK(cur, row, 4 + l4);
            S[mm] = mfma16(kf0, q0, S[mm]);
            S[mm] = mfma16(kf1, q1, S[mm]);
        }
        bf16x8 af[2];
        smpack(S, mrun, lrun, O, af, kvb == qt, kv0, qrow);
#pragma unroll
        for (int ks = 0; ks < 2; ++ks)
#pragma unroll
            for (int c2 = 0; c2 < 4; ++c2) {
                bf16x8 vf = ldV(cur, c2 * 16 + l15, ks * 4 + l4);
                O[c2] = mfma16(af[ks], vf, O[c2]);
            }
        __builtin_amdgcn_s_barrier();   // protect buffer overwrite by next stage
    }

    // epilogue: O rows are q'=l4*4+i, cols d=c2*16+l15
#pragma unroll
    for (int i = 0; i < 4; ++i) {
        float lv = __shfl(lrun, idxO[i]);
        float rcp = 1.f / lv;
        int qg = qt * 64 + wave * 16 + l4 * 4 + i;
#pragma unroll
        for (int c2 = 0; c2 < 4; ++c2)
            ao[(size_t)(b * 2048 + qg) * 1024 + h * 64 + c2 * 16 + l15] = f2bf(O[c2][i] * rcp);
    }
}

// ---------- launch ----------
extern "C" void kernel_launch(void* const* d_in, const int* in_sizes, int n_in,
                              void* d_out, int out_size, void* d_ws, size_t ws_size,
                              hipStream_t stream) {
    const float* x    = (const float*)d_in[0];   // (2,2048,1024)
    const float* Wqkv = (const float*)d_in[1];   // (1024,3072)
    const float* Wout = (const float*)d_in[2];   // (1024,1024)
    float* out = (float*)d_out;                  // (2,2048,1024)
    char* ws = (char*)d_ws;

    u16*   xb  = (u16*)(ws + 0);            // 8 MB  (4096x1024 bf16)
    u16*   Wtq = (u16*)(ws + 8388608);      // 6 MB  (3072x1024 bf16)
    u16*   Wto = (u16*)(ws + 14680064);     // 2 MB  (1024x1024 bf16)
    u16*   qb  = (u16*)(ws + 67108864);     // 8 MB  (B,H,T,Dh bf16, pre-scaled)
    u16*   kb  = (u16*)(ws + 75497472);     // 8 MB
    u16*   vt  = (u16*)(ws + 83886080);     // 8 MB  (B,H,Dh,T bf16)
    float* tab = (float*)(ws + 92274688);   // 512 KB sin/cos table
    u16*   ao  = (u16*)(ws + 0);            // reuse xb region (gemm_qkv done by then)

    cvt_bf16<<<dim3(4096), dim3(256), 0, stream>>>(x, xb);
    transpose_cvt<<<dim3(96, 32), dim3(256), 0, stream>>>(Wqkv, Wtq, 1024, 3072);
    transpose_cvt<<<dim3(32, 32), dim3(256), 0, stream>>>(Wout, Wto, 1024, 1024);
    rope_tab<<<dim3(256), dim3(256), 0, stream>>>(tab);
    gemm_qkv<<<dim3(24, 32), dim3(512), 0, stream>>>(xb, Wtq, tab, qb, kb, vt, 4096, 3072, 1024);
    flash10<<<dim3(1024), dim3(256), 0, stream>>>(qb, kb, vt, ao);
    gemm_bt_n64<<<dim3(16, 32), dim3(512), 0, stream>>>(ao, Wto, out, 4096, 1024, 1024);
}